// Round 11
// baseline (581.847 us; speedup 1.0000x reference)
//
#include <hip/hip_runtime.h>

#define EPSF 1e-5f

typedef __attribute__((ext_vector_type(8)))  short short8;
typedef __attribute__((ext_vector_type(4)))  float f32x4;
typedef __attribute__((ext_vector_type(16))) float f32x16;

__device__ __forceinline__ unsigned short f2bf(float f) {
  unsigned u = __builtin_bit_cast(unsigned, f);
  unsigned r = (u + 0x7FFFu + ((u >> 16) & 1u)) >> 16;   // RNE
  return (unsigned short)r;
}
__device__ __forceinline__ float bf2f(unsigned short h) {
  unsigned u = ((unsigned)h) << 16;
  return __builtin_bit_cast(float, u);
}

// ---------------------------------------------------------------------------
// Weight pre-transpose: W[K][C][3][3] fp32 -> Wt[tap][C/8][K][8] bf16
// ---------------------------------------------------------------------------
__global__ void wt_prep(const float* __restrict__ w, unsigned short* __restrict__ wt,
                        int C, int K) {
  int C8 = C >> 3;
  int idx = blockIdx.x * 256 + threadIdx.x;
  if (idx >= K * C8) return;
  int k = idx / C8, ch = idx - k * C8;
  const float* src = w + ((size_t)k * C + ch * 8) * 9;
#pragma unroll
  for (int tap = 0; tap < 9; ++tap) {
    short8 v;
#pragma unroll
    for (int cl = 0; cl < 8; ++cl) v[cl] = (short)f2bf(src[cl * 9 + tap]);
    *(short8*)(wt + ((size_t)(tap * C8 + ch) * K + k) * 8) = v;
  }
}

// ---------------------------------------------------------------------------
// fp32 NCHW -> bf16 NC8HW8
// ---------------------------------------------------------------------------
__global__ void nchw_to_nc8(const float* __restrict__ in, unsigned short* __restrict__ out,
                            int C8, int HW, int total) {
  int idx = blockIdx.x * 256 + threadIdx.x;
  if (idx >= total) return;
  int pix = idx % HW; int t = idx / HW; int ch = t % C8; int n = t / C8;
  const float* s = in + ((size_t)(n * C8 + ch) * 8) * HW + pix;
  short8 v;
#pragma unroll
  for (int cl = 0; cl < 8; ++cl) v[cl] = (short)f2bf(s[(size_t)cl * HW]);
  *(short8*)(out + (size_t)idx * 8) = v;
}

// ===========================================================================
// Conv kernel A (proven): wave = 64 kchans x 64 pix (mf=2). Used for the 32x32
// layers (L1/L2, need deep split-C) and L9 (K=64).
// ===========================================================================
__global__ __launch_bounds__(256) void conv3x3_mfma(
    const unsigned short* __restrict__ act, const unsigned short* __restrict__ wt,
    const float* __restrict__ bias, unsigned short* __restrict__ out,
    float* __restrict__ partial, int C, int K, int H, int W, int S) {
  const int C8 = C >> 3, K8 = K >> 3;
  const int HW = H * W;
  const int tid = threadIdx.x;
  const int lane = tid & 63, wid = tid >> 6;
  const int l31 = lane & 31, lhi = lane >> 5;
  const int w0 = blockIdx.x * 16, h0 = blockIdx.y * 16;
  const int kbn = K >> 6;
  int zz = blockIdx.z;
  const int sp = zz % S; zz /= S;
  const int kb = zz % kbn;
  const int n  = zz / kbn;
  const int k0 = kb * 64;

  __shared__ __align__(16) unsigned short smem[24576];  // 2 x 1536 slots x 16B
  __shared__ float sbias[64];
  if (tid < 64) sbias[tid] = bias[k0 + tid];

  int g16[6];
#pragma unroll
  for (int it = 0; it < 6; ++it) {
    int slot = it * 256 + wid * 64 + lane;
    int s = slot < 1296 ? slot : 0;
    int chi = s / 324; int r = s - chi * 324;
    int y = r / 18, x = r - y * 18;
    int gy = h0 - 1 + y; gy = gy < 0 ? -gy : (gy >= H ? 2 * H - 2 - gy : gy);
    int gx = w0 - 1 + x; gx = gx < 0 ? -gx : (gx >= W ? 2 * W - 2 - gx : gx);
    g16[it] = ((n * C8 + chi) * H + gy) * W + gx;
  }

  const int pbase = wid * 64;
  int pb[2];
#pragma unroll
  for (int nf = 0; nf < 2; ++nf) {
    int p = pbase + nf * 32 + l31;
    pb[nf] = (p >> 4) * 18 + (p & 15);
  }
  int bb8[2][2];
#pragma unroll
  for (int ks = 0; ks < 2; ++ks)
#pragma unroll
    for (int nf = 0; nf < 2; ++nf)
      bb8[ks][nf] = ((ks * 2 + lhi) * 324 + pb[nf]) * 8;

  const size_t tapStep   = (size_t)C8 * K * 8;
  const size_t chunkStep = (size_t)4 * K * 8;
  const int cps = (C >> 5) / S;
  const int c0 = sp * cps;
  const unsigned short* ap[2][2];
#pragma unroll
  for (int ks = 0; ks < 2; ++ks)
#pragma unroll
    for (int mf = 0; mf < 2; ++mf)
      ap[ks][mf] = wt + ((size_t)(c0 * 4) * K
                  + (size_t)((ks * 2 + lhi) * K + k0 + mf * 32 + l31)) * 8;

  f32x16 acc[2][2] = {};

#define STAGE(BSEL, CI)                                                          \
  {                                                                              \
    _Pragma("unroll")                                                            \
    for (int it = 0; it < 6; ++it) {                                             \
      const unsigned short* g = act + ((size_t)g16[it] + (size_t)(CI) * 4 * HW) * 8; \
      __builtin_amdgcn_global_load_lds(                                          \
          (const __attribute__((address_space(1))) unsigned int*)g,              \
          (__attribute__((address_space(3))) unsigned int*)                      \
              &smem[(BSEL) * 12288 + (it * 256 + wid * 64) * 8],                 \
          16, 0, 0);                                                             \
    }                                                                            \
  }

  STAGE(0, c0)

  for (int i = 0; i < cps; ++i) {
    __syncthreads();
    const int boff = (i & 1) * 12288;
    const unsigned short* aw[2][2];
    short8 acur[2][2], anx[2][2];
#pragma unroll
    for (int ks = 0; ks < 2; ++ks)
#pragma unroll
      for (int mf = 0; mf < 2; ++mf) {
        aw[ks][mf] = ap[ks][mf];
        acur[ks][mf] = *(const short8*)aw[ks][mf];
        aw[ks][mf] += tapStep;
      }
#pragma unroll
    for (int tap = 0; tap < 9; ++tap) {
      if (tap < 8) {
#pragma unroll
        for (int ks = 0; ks < 2; ++ks)
#pragma unroll
          for (int mf = 0; mf < 2; ++mf) {
            anx[ks][mf] = *(const short8*)aw[ks][mf];
            aw[ks][mf] += tapStep;
          }
      }
      if (tap == 7 && i + 1 < cps) STAGE((i & 1) ^ 1, c0 + i + 1)
      const int ty = tap / 3, txx = tap - ty * 3;
      const int toff = (ty * 18 + txx) * 8;
      short8 b[2][2];
#pragma unroll
      for (int ks = 0; ks < 2; ++ks)
#pragma unroll
        for (int nf = 0; nf < 2; ++nf)
          b[nf][ks] = *(const short8*)&smem[boff + bb8[ks][nf] + toff];
#pragma unroll
      for (int ks = 0; ks < 2; ++ks)
#pragma unroll
        for (int mf = 0; mf < 2; ++mf)
#pragma unroll
          for (int nf = 0; nf < 2; ++nf)
            acc[mf][nf] = __builtin_amdgcn_mfma_f32_32x32x16_bf16(
                acur[ks][mf], b[nf][ks], acc[mf][nf], 0, 0, 0);
#pragma unroll
      for (int ks = 0; ks < 2; ++ks)
#pragma unroll
        for (int mf = 0; mf < 2; ++mf)
          acur[ks][mf] = anx[ks][mf];
    }
#pragma unroll
    for (int ks = 0; ks < 2; ++ks)
#pragma unroll
      for (int mf = 0; mf < 2; ++mf)
        ap[ks][mf] += chunkStep;
  }

  if (S > 1) {
    float* P = partial + (size_t)sp * ((size_t)4 * K * HW);
#pragma unroll
    for (int mf = 0; mf < 2; ++mf)
#pragma unroll
      for (int nf = 0; nf < 2; ++nf) {
        int p = pbase + nf * 32 + l31;
        int gp = (h0 + (p >> 4)) * W + (w0 + (p & 15));
#pragma unroll
        for (int q = 0; q < 4; ++q) {
          size_t ad = ((size_t)(n * K8 + (k0 >> 3) + mf * 4 + q) * HW + gp) * 8 + 4 * lhi;
          f32x4 v = { acc[mf][nf][4 * q], acc[mf][nf][4 * q + 1],
                      acc[mf][nf][4 * q + 2], acc[mf][nf][4 * q + 3] };
          *(f32x4*)(P + ad) = v;
        }
      }
    return;
  }

  __syncthreads();
#pragma unroll
  for (int mf = 0; mf < 2; ++mf)
#pragma unroll
    for (int nf = 0; nf < 2; ++nf) {
      int pix = pbase + nf * 32 + l31;
#pragma unroll
      for (int rp = 0; rp < 8; ++rp) {
        const int r0 = rp * 2;
        int row0 = (r0 & 3) + 8 * (r0 >> 2) + 4 * lhi;
        int c64 = mf * 32 + row0;
        float v0 = acc[mf][nf][r0]     + sbias[c64];
        float v1 = acc[mf][nf][r0 + 1] + sbias[c64 + 1];
        v0 = v0 > 0.f ? v0 : 0.f;
        v1 = v1 > 0.f ? v1 : 0.f;
        unsigned pk = (unsigned)f2bf(v0) | ((unsigned)f2bf(v1) << 16);
        int chh = mf * 4 + (r0 >> 2);
        int clo = (r0 & 3) + 4 * lhi;
        *(unsigned*)&smem[((chh * 256 + pix) * 8 + clo)] = pk;
      }
    }
  __syncthreads();
#pragma unroll
  for (int i = 0; i < 8; ++i) {
    int slot = i * 256 + tid;
    int ch = slot >> 8;
    int p = slot & 255;
    int py = p >> 4, px = p & 15;
    short8 v = *(const short8*)&smem[slot * 8];
    *(short8*)(out + (((size_t)(n * K8 + (k0 >> 3) + ch) * H + h0 + py) * W + w0 + px) * 8) = v;
  }
#undef STAGE
}

// ===========================================================================
// Conv kernel B (round-11): wave = 128 kchans x 64 pix (mf=4) — halves LDS
// B-read traffic per output. K-tile 128/block. Used for L3..L8.
// ===========================================================================
__global__ __launch_bounds__(256) void conv3x3_mfma_w128(
    const unsigned short* __restrict__ act, const unsigned short* __restrict__ wt,
    const float* __restrict__ bias, unsigned short* __restrict__ out,
    float* __restrict__ partial, int C, int K, int H, int W, int S) {
  const int C8 = C >> 3, K8 = K >> 3;
  const int HW = H * W;
  const int tid = threadIdx.x;
  const int lane = tid & 63, wid = tid >> 6;
  const int l31 = lane & 31, lhi = lane >> 5;
  const int w0 = blockIdx.x * 16, h0 = blockIdx.y * 16;
  const int kbn = K >> 7;
  int zz = blockIdx.z;
  const int sp = zz % S; zz /= S;
  const int kb = zz % kbn;
  const int n  = zz / kbn;
  const int k0 = kb * 128;

  __shared__ __align__(16) unsigned short smem[24576];
  __shared__ float sbias[128];
  if (tid < 128) sbias[tid] = bias[k0 + tid];

  int g16[6];
#pragma unroll
  for (int it = 0; it < 6; ++it) {
    int slot = it * 256 + wid * 64 + lane;
    int s = slot < 1296 ? slot : 0;
    int chi = s / 324; int r = s - chi * 324;
    int y = r / 18, x = r - y * 18;
    int gy = h0 - 1 + y; gy = gy < 0 ? -gy : (gy >= H ? 2 * H - 2 - gy : gy);
    int gx = w0 - 1 + x; gx = gx < 0 ? -gx : (gx >= W ? 2 * W - 2 - gx : gx);
    g16[it] = ((n * C8 + chi) * H + gy) * W + gx;
  }

  const int pbase = wid * 64;
  int pb[2];
#pragma unroll
  for (int nf = 0; nf < 2; ++nf) {
    int p = pbase + nf * 32 + l31;
    pb[nf] = (p >> 4) * 18 + (p & 15);
  }
  int bb8[2][2];
#pragma unroll
  for (int ks = 0; ks < 2; ++ks)
#pragma unroll
    for (int nf = 0; nf < 2; ++nf)
      bb8[ks][nf] = ((ks * 2 + lhi) * 324 + pb[nf]) * 8;

  const size_t tapStep   = (size_t)C8 * K * 8;
  const size_t chunkStep = (size_t)4 * K * 8;
  const int cps = (C >> 5) / S;
  const int c0 = sp * cps;
  // A addressing: one rolling base + 8 lane-constant int offsets (shorts)
  int aoff[2][4];
#pragma unroll
  for (int ks = 0; ks < 2; ++ks)
#pragma unroll
    for (int mf = 0; mf < 4; ++mf)
      aoff[ks][mf] = ((ks * 2 + lhi) * K + k0 + mf * 32 + l31) * 8;
  const unsigned short* abase = wt + (size_t)(c0 * 4) * K * 8;

  f32x16 acc[4][2] = {};

#define STAGE(BSEL, CI)                                                          \
  {                                                                              \
    _Pragma("unroll")                                                            \
    for (int it = 0; it < 6; ++it) {                                             \
      const unsigned short* g = act + ((size_t)g16[it] + (size_t)(CI) * 4 * HW) * 8; \
      __builtin_amdgcn_global_load_lds(                                          \
          (const __attribute__((address_space(1))) unsigned int*)g,              \
          (__attribute__((address_space(3))) unsigned int*)                      \
              &smem[(BSEL) * 12288 + (it * 256 + wid * 64) * 8],                 \
          16, 0, 0);                                                             \
    }                                                                            \
  }

  STAGE(0, c0)

  for (int i = 0; i < cps; ++i) {
    __syncthreads();
    const int boff = (i & 1) * 12288;
    const unsigned short* atap = abase;
#pragma unroll
    for (int tap = 0; tap < 9; ++tap) {
      short8 a[2][4];
#pragma unroll
      for (int ks = 0; ks < 2; ++ks)
#pragma unroll
        for (int mf = 0; mf < 4; ++mf)
          a[ks][mf] = *(const short8*)(atap + aoff[ks][mf]);
      // after the LAST A-issue of the chunk -> A-waits never drain staging
      if (tap == 8 && i + 1 < cps) STAGE((i & 1) ^ 1, c0 + i + 1)
      const int ty = tap / 3, txx = tap - ty * 3;
      const int toff = (ty * 18 + txx) * 8;
      short8 b[2][2];
#pragma unroll
      for (int ks = 0; ks < 2; ++ks)
#pragma unroll
        for (int nf = 0; nf < 2; ++nf)
          b[nf][ks] = *(const short8*)&smem[boff + bb8[ks][nf] + toff];
#pragma unroll
      for (int ks = 0; ks < 2; ++ks)
#pragma unroll
        for (int mf = 0; mf < 4; ++mf)
#pragma unroll
          for (int nf = 0; nf < 2; ++nf)
            acc[mf][nf] = __builtin_amdgcn_mfma_f32_32x32x16_bf16(
                a[ks][mf], b[nf][ks], acc[mf][nf], 0, 0, 0);
      atap += tapStep;
    }
    abase += chunkStep;
  }

  if (S > 1) {
    float* P = partial + (size_t)sp * ((size_t)4 * K * HW);
#pragma unroll
    for (int mf = 0; mf < 4; ++mf)
#pragma unroll
      for (int nf = 0; nf < 2; ++nf) {
        int p = pbase + nf * 32 + l31;
        int gp = (h0 + (p >> 4)) * W + (w0 + (p & 15));
#pragma unroll
        for (int q = 0; q < 4; ++q) {
          size_t ad = ((size_t)(n * K8 + (k0 >> 3) + mf * 4 + q) * HW + gp) * 8 + 4 * lhi;
          f32x4 v = { acc[mf][nf][4 * q], acc[mf][nf][4 * q + 1],
                      acc[mf][nf][4 * q + 2], acc[mf][nf][4 * q + 3] };
          *(f32x4*)(P + ad) = v;
        }
      }
    return;
  }

  // S==1 epilogue: two 64-chan transpose passes through 32KB of smem
#pragma unroll
  for (int half = 0; half < 2; ++half) {
    __syncthreads();
#pragma unroll
    for (int m2 = 0; m2 < 2; ++m2) {
      const int mf = half * 2 + m2;
#pragma unroll
      for (int nf = 0; nf < 2; ++nf) {
        int pix = pbase + nf * 32 + l31;
#pragma unroll
        for (int rp = 0; rp < 8; ++rp) {
          const int r0 = rp * 2;
          int row0 = (r0 & 3) + 8 * (r0 >> 2) + 4 * lhi;
          int cl = half * 64 + m2 * 32 + row0;
          float v0 = acc[mf][nf][r0]     + sbias[cl];
          float v1 = acc[mf][nf][r0 + 1] + sbias[cl + 1];
          v0 = v0 > 0.f ? v0 : 0.f;
          v1 = v1 > 0.f ? v1 : 0.f;
          unsigned pk = (unsigned)f2bf(v0) | ((unsigned)f2bf(v1) << 16);
          int chh = m2 * 4 + (r0 >> 2);
          int clo = (r0 & 3) + 4 * lhi;
          *(unsigned*)&smem[((chh * 256 + pix) * 8 + clo)] = pk;
        }
      }
    }
    __syncthreads();
#pragma unroll
    for (int i = 0; i < 8; ++i) {
      int slot = i * 256 + tid;
      int ch = slot >> 8;
      int p = slot & 255;
      int py = p >> 4, px = p & 15;
      short8 v = *(const short8*)&smem[slot * 8];
      *(short8*)(out + (((size_t)(n * K8 + (k0 >> 3) + half * 8 + ch) * H + h0 + py)
                        * W + w0 + px) * 8) = v;
    }
  }
#undef STAGE
}

// ---------------------------------------------------------------------------
// combine split-C partials: sum + bias + relu + pack bf16 NC8HW8
// ---------------------------------------------------------------------------
__global__ void combine_bias_relu(const float* __restrict__ P, const float* __restrict__ bias,
                                  unsigned short* __restrict__ out, int S, int K8, int HW,
                                  int total8) {
  int idx = blockIdx.x * 256 + threadIdx.x;
  if (idx >= total8) return;
  int k8 = (idx / HW) % K8;
  const float* p = P + (size_t)idx * 8;
  size_t stride = (size_t)total8 * 8;
  float v[8];
#pragma unroll
  for (int c = 0; c < 8; ++c) v[c] = p[c];
  for (int s = 1; s < S; ++s) {
#pragma unroll
    for (int c = 0; c < 8; ++c) v[c] += p[(size_t)s * stride + c];
  }
  short8 r;
#pragma unroll
  for (int c = 0; c < 8; ++c) {
    float x = v[c] + bias[k8 * 8 + c];
    x = x > 0.f ? x : 0.f;
    r[c] = (short)f2bf(x);
  }
  *(short8*)(out + (size_t)idx * 8) = r;
}

// ---------------------------------------------------------------------------
// Wavelet unpool fused with rpad(1)+crop shift, NC8HW8 bf16 ll / fp32 bands.
// ---------------------------------------------------------------------------
__global__ void unpool_shift_nc8(const unsigned short* __restrict__ ll,
                                 const float* __restrict__ lh, const float* __restrict__ hl,
                                 const float* __restrict__ hh, unsigned short* __restrict__ out,
                                 int C8, int Hh, int Wh, int total) {
  int idx = blockIdx.x * 256 + threadIdx.x;
  if (idx >= total) return;
  const int Ho = 2 * Hh, Wo = 2 * Wh;
  int j = idx % Wo; int t = idx / Wo;
  int i = t % Ho; t /= Ho;
  int ch = t % C8; int n = t / C8;
  int si = (i == 0) ? 1 : i - 1;
  int sj = (j == 0) ? 1 : j - 1;
  float sa = (si & 1) ? 1.f : -1.f;
  float sb = (sj & 1) ? 1.f : -1.f;
  int hy = si >> 1, hx = sj >> 1;
  size_t HWh = (size_t)Hh * Wh;
  const unsigned short* lp = ll + ((size_t)(n * C8 + ch) * HWh + hy * Wh + hx) * 8;
  size_t bb = ((size_t)(n * C8 + ch) * 8 * Hh + hy) * Wh + hx;
  short8 res;
#pragma unroll
  for (int cl = 0; cl < 8; ++cl) {
    float v = 0.5f * (bf2f(lp[cl]) + sb * lh[bb + cl * HWh] + sa * hl[bb + cl * HWh]
                      + sa * sb * hh[bb + cl * HWh]);
    res[cl] = (short)f2bf(v);
  }
  *(short8*)(out + (size_t)idx * 8) = res;
}

// ---------------------------------------------------------------------------
// Final unpool + rpad, pair-vectorized: ll = t12 (bf16 NC8HW8, K=64),
// out fp32 NCHW (4,64,258,258). One thread per (img, row, col-pair).
// ---------------------------------------------------------------------------
__global__ void unpool_rpad_final_v2(const unsigned short* __restrict__ ll,
                                     const float* __restrict__ lh, const float* __restrict__ hl,
                                     const float* __restrict__ hh, float* __restrict__ out) {
  const int img = blockIdx.y;                 // n*64 + c
  int idx = blockIdx.x * 256 + threadIdx.x;   // over 258 rows * 129 pairs
  if (idx >= 258 * 129) return;
  int i = idx / 129, jm = idx - i * 129;
  const int n = img >> 6, c = img & 63;

  int si = (i == 0) ? 1 : i - 1; if (si >= 256) si = 254;
  float sa = (si & 1) ? 1.f : -1.f;
  int hy = si >> 1;
  int hx0 = (jm == 0) ? 0 : jm - 1;
  int hx1 = (jm == 128) ? 127 : jm;

  size_t lb = ((size_t)(n * 8 + (c >> 3)) * 16384 + hy * 128) * 8 + (c & 7);
  float lv0 = bf2f(ll[lb + hx0 * 8]);
  float lv1 = bf2f(ll[lb + hx1 * 8]);

  size_t bb = ((size_t)img * 128 + hy) * 128;
  float l0 = lh[bb + hx0], g0 = hl[bb + hx0], h0 = hh[bb + hx0];
  float l1 = lh[bb + hx1], g1 = hl[bb + hx1], h1 = hh[bb + hx1];
  float o0 = 0.5f * (lv0 + l0 + sa * (g0 + h0));
  float o1 = 0.5f * (lv1 - l1 + sa * (g1 - h1));
  float2 r = make_float2(o0, o1);
  *(float2*)&out[((size_t)img * 258 + i) * 258 + 2 * jm] = r;
}

// ---------------------------------------------------------------------------
// AdaIN support
// ---------------------------------------------------------------------------
__global__ void pack_masks(const float* __restrict__ cmask, const float* __restrict__ smask,
                           unsigned* __restrict__ cbits, unsigned* __restrict__ sbits) {
  int idx = blockIdx.x * 256 + threadIdx.x;
  if (idx >= 16384) return;
  int h = idx >> 7, w = idx & 127;
  unsigned cb = 0, sb = 0;
#pragma unroll
  for (int k = 0; k < 8; ++k) {
    int off = (k * 256 + 2 * h) * 256 + 2 * w;
    if (cmask[off] != 0.f) cb |= (1u << k);
    if (smask[off] != 0.f) sb |= (1u << k);
  }
  cbits[idx] = cb;
  sbits[idx] = sb;
}

__global__ __launch_bounds__(1024) void mask_flags(
    const float* __restrict__ cmask, const float* __restrict__ smask,
    float* __restrict__ flagc, float* __restrict__ sany) {
  int k = blockIdx.x;
  const float* cm = cmask + (size_t)k * 65536;
  const float* sm = smask + (size_t)k * 65536;
  int ca = 0, sa = 0;
  for (int i = threadIdx.x; i < 65536; i += 1024) {
    ca |= (cm[i] != 0.f);
    sa |= (sm[i] != 0.f);
  }
#pragma unroll
  for (int off = 32; off > 0; off >>= 1) {
    ca |= __shfl_xor(ca, off, 64);
    sa |= __shfl_xor(sa, off, 64);
  }
  __shared__ int rc[16], rs[16];
  int wv = threadIdx.x >> 6;
  if ((threadIdx.x & 63) == 0) { rc[wv] = ca; rs[wv] = sa; }
  __syncthreads();
  if (threadIdx.x == 0) {
    int c = 0, s = 0;
#pragma unroll
    for (int i = 0; i < 16; ++i) { c |= rc[i]; s |= rs[i]; }
    flagc[k] = c ? 1.f : 0.f;
    sany[k]  = s ? 1.f : 0.f;
  }
}

__global__ __launch_bounds__(256) void masked_stats_bf16(
    const unsigned short* __restrict__ feat, const unsigned* __restrict__ bits,
    float* __restrict__ outp, int NC) {
  constexpr int NV = 24;
  int b = blockIdx.x; int n = b >> 7, c = b & 127;
  const int sp = blockIdx.y;
  const unsigned short* f = feat + (size_t)(n * 16 + (c >> 3)) * 16384 * 8 + (c & 7);
  float acc[NV];
#pragma unroll
  for (int j = 0; j < NV; ++j) acc[j] = 0.f;
  const int p0 = sp * 4096;
  for (int it = 0; it < 16; ++it) {
    int i = p0 + it * 256 + threadIdx.x;
    float v = bf2f(f[(size_t)i * 8]) + EPSF;
    float nz = (v != 0.f) ? 1.f : 0.f;
    float v2 = v * v;
    unsigned m = bits[i];
#pragma unroll
    for (int k = 0; k < 8; ++k) {
      float mk = (float)((m >> k) & 1u);
      acc[k * 3 + 0] += mk * nz;
      acc[k * 3 + 1] += mk * v;
      acc[k * 3 + 2] += mk * v2;
    }
  }
#pragma unroll
  for (int j = 0; j < NV; ++j) {
    float v = acc[j];
#pragma unroll
    for (int off = 32; off > 0; off >>= 1) v += __shfl_xor(v, off, 64);
    acc[j] = v;
  }
  __shared__ float red[4][NV];
  int lane = threadIdx.x & 63, wv = threadIdx.x >> 6;
  if (lane == 0) {
#pragma unroll
    for (int j = 0; j < NV; ++j) red[wv][j] = acc[j];
  }
  __syncthreads();
  int tid = threadIdx.x;
  if (tid < NV) {
    float s = red[0][tid] + red[1][tid] + red[2][tid] + red[3][tid];
    outp[(sp * NV + tid) * NC + b] = s;
  }
}

__global__ __launch_bounds__(256) void masked_stats_f32g(
    const float* __restrict__ feat, const unsigned* __restrict__ bits,
    float* __restrict__ sstp, float* __restrict__ gstp, int NC) {
  constexpr int NV = 27;
  const int b = blockIdx.x;
  const int sp = blockIdx.y;
  const float* f = feat + (size_t)b * 16384;
  float acc[NV];
#pragma unroll
  for (int j = 0; j < NV; ++j) acc[j] = 0.f;
  const int p0 = sp * 4096;
#pragma unroll 1
  for (int it = 0; it < 4; ++it) {
    int p = p0 + it * 1024 + threadIdx.x * 4;
    float4 v4 = *(const float4*)&f[p];
    uint4 m4 = *(const uint4*)&bits[p];
#pragma unroll
    for (int e = 0; e < 4; ++e) {
      float v = (&v4.x)[e] + EPSF;
      unsigned m = (&m4.x)[e];
      float nz = (v != 0.f) ? 1.f : 0.f;
      float v2 = v * v;
#pragma unroll
      for (int k = 0; k < 8; ++k) {
        float mk = (float)((m >> k) & 1u);
        acc[k * 3 + 0] += mk * nz;
        acc[k * 3 + 1] += mk * v;
        acc[k * 3 + 2] += mk * v2;
      }
      acc[24] += nz; acc[25] += v; acc[26] += v2;
    }
  }
#pragma unroll
  for (int j = 0; j < NV; ++j) {
    float v = acc[j];
#pragma unroll
    for (int off = 32; off > 0; off >>= 1) v += __shfl_xor(v, off, 64);
    acc[j] = v;
  }
  __shared__ float red[4][NV];
  int lane = threadIdx.x & 63, wv = threadIdx.x >> 6;
  if (lane == 0) {
#pragma unroll
    for (int j = 0; j < NV; ++j) red[wv][j] = acc[j];
  }
  __syncthreads();
  int tid = threadIdx.x;
  if (tid < NV) {
    float s = red[0][tid] + red[1][tid] + red[2][tid] + red[3][tid];
    if (tid < 24) sstp[(sp * 24 + tid) * NC + b] = s;
    else gstp[(sp * 3 + (tid - 24)) * NC + b] = s;
  }
}

__global__ void finalize_ss(const float* __restrict__ cstp, const float* __restrict__ sstp,
                            const float* __restrict__ gstp, const float* __restrict__ flagc,
                            const float* __restrict__ sany,
                            float* __restrict__ scal, float* __restrict__ shft, int NC) {
  int idx = blockIdx.x * blockDim.x + threadIdx.x;
  if (idx >= 8 * NC) return;
  int k = idx / NC, b = idx - k * NC;
  bool useg = (sany[k] == 0.f);
  float ccnt = 0.f, cs1 = 0.f, cs2 = 0.f, scnt = 0.f, ss1 = 0.f, ss2 = 0.f;
#pragma unroll
  for (int s = 0; s < 4; ++s) {
    const float* cp = cstp + s * 24 * NC;
    ccnt += cp[(k * 3 + 0) * NC + b];
    cs1  += cp[(k * 3 + 1) * NC + b];
    cs2  += cp[(k * 3 + 2) * NC + b];
    if (useg) {
      const float* gp = gstp + s * 3 * NC;
      scnt += gp[0 * NC + b]; ss1 += gp[1 * NC + b]; ss2 += gp[2 * NC + b];
    } else {
      const float* spp = sstp + s * 24 * NC;
      scnt += spp[(k * 3 + 0) * NC + b];
      ss1  += spp[(k * 3 + 1) * NC + b];
      ss2  += spp[(k * 3 + 2) * NC + b];
    }
  }
  float cmn  = cs1 / fmaxf(ccnt, 1.f);
  float cvv  = (cs2 - ccnt * cmn * cmn) / fmaxf(ccnt - 1.f, 1.f) + EPSF;
  float cstd = sqrtf(cvv);
  float smn  = ss1 / fmaxf(scnt, 1.f);
  float svv  = (ss2 - scnt * smn * smn) / fmaxf(scnt - 1.f, 1.f) + EPSF;
  float sstd = sqrtf(svv);
  float fl = flagc[k];
  float r  = sstd / cstd;
  scal[idx] = fl * r;
  shft[idx] = fl * (smn - cmn * r);
}

__global__ void adain_apply_nc8(const unsigned short* __restrict__ content,
                                const unsigned* __restrict__ bits,
                                const float* __restrict__ scal, const float* __restrict__ shft,
                                unsigned short* __restrict__ out) {
  int ch = blockIdx.x & 15, n = blockIdx.x >> 4;
  __shared__ float ssc[8][8], ssh[8][8];
  if (threadIdx.x < 64) {
    int k = threadIdx.x >> 3, cl = threadIdx.x & 7;
    int c = ch * 8 + cl;
    ssc[k][cl] = scal[k * 512 + n * 128 + c];
    ssh[k][cl] = shft[k * 512 + n * 128 + c];
  }
  __syncthreads();
  const unsigned short* src = content + (size_t)blockIdx.x * 16384 * 8;
  unsigned short* dst = out + (size_t)blockIdx.x * 16384 * 8;
  const int p0 = blockIdx.y * 1024;
  for (int p = p0 + threadIdx.x; p < p0 + 1024; p += 256) {
    unsigned m = bits[p];
    float sc[8], sh[8];
#pragma unroll
    for (int cl = 0; cl < 8; ++cl) { sc[cl] = 0.f; sh[cl] = 0.f; }
    for (int k = 0; k < 8; ++k) {
      if ((m >> k) & 1u) {
#pragma unroll
        for (int cl = 0; cl < 8; ++cl) { sc[cl] += ssc[k][cl]; sh[cl] += ssh[k][cl]; }
      }
    }
    short8 v = *(const short8*)(src + (size_t)p * 8);
    short8 r;
#pragma unroll
    for (int cl = 0; cl < 8; ++cl) {
      float f = bf2f((unsigned short)v[cl]) + EPSF;
      r[cl] = (short)f2bf(f * sc[cl] + sh[cl]);
    }
    *(short8*)(dst + (size_t)p * 8) = r;
  }
}

// ---------------------------------------------------------------------------
static void launch_conv(const unsigned short* act, const unsigned short* wt,
                        const float* bias, unsigned short* out, float* partial,
                        int C, int K, int H, int W, int S, hipStream_t st) {
  dim3 g(W / 16, H / 16, 4 * (K / 64) * S);
  conv3x3_mfma<<<g, 256, 0, st>>>(act, wt, bias, out, partial, C, K, H, W, S);
  if (S > 1) {
    int total8 = 4 * (K >> 3) * H * W;
    combine_bias_relu<<<(total8 + 255) / 256, 256, 0, st>>>(
        partial, bias, out, S, K >> 3, H * W, total8);
  }
}

static void launch_conv_w128(const unsigned short* act, const unsigned short* wt,
                             const float* bias, unsigned short* out, float* partial,
                             int C, int K, int H, int W, int S, hipStream_t st) {
  dim3 g(W / 16, H / 16, 4 * (K / 128) * S);
  conv3x3_mfma_w128<<<g, 256, 0, st>>>(act, wt, bias, out, partial, C, K, H, W, S);
  if (S > 1) {
    int total8 = 4 * (K >> 3) * H * W;
    combine_bias_relu<<<(total8 + 255) / 256, 256, 0, st>>>(
        partial, bias, out, S, K >> 3, H * W, total8);
  }
}

extern "C" void kernel_launch(void* const* d_in, const int* in_sizes, int n_in,
                              void* d_out, int out_size, void* d_ws, size_t ws_size,
                              hipStream_t stream) {
  const float* f1   = (const float*)d_in[0];
  const float* f2   = (const float*)d_in[1];
  const float* s2lh = (const float*)d_in[2];
  const float* s2hl = (const float*)d_in[3];
  const float* s2hh = (const float*)d_in[4];
  const float* s1lh = (const float*)d_in[5];
  const float* s1hl = (const float*)d_in[6];
  const float* s1hh = (const float*)d_in[7];
  const float* s0lh = (const float*)d_in[8];
  const float* s0hl = (const float*)d_in[9];
  const float* s0hh = (const float*)d_in[10];
  const float* cmask = (const float*)d_in[11];
  const float* smask = (const float*)d_in[12];
  const float* w11 = (const float*)d_in[13]; const float* b11 = (const float*)d_in[14];
  const float* w12 = (const float*)d_in[15]; const float* b12 = (const float*)d_in[16];
  const float* w21 = (const float*)d_in[17]; const float* b21 = (const float*)d_in[18];
  const float* w22 = (const float*)d_in[19]; const float* b22 = (const float*)d_in[20];
  const float* w23 = (const float*)d_in[21]; const float* b23 = (const float*)d_in[22];
  const float* w24 = (const float*)d_in[23]; const float* b24 = (const float*)d_in[24];
  const float* w31 = (const float*)d_in[25]; const float* b31 = (const float*)d_in[26];
  const float* w32 = (const float*)d_in[27]; const float* b32 = (const float*)d_in[28];
  const float* w33 = (const float*)d_in[29]; const float* b33 = (const float*)d_in[30];

  // d_out layout: A bf16 [0,16.78MB) B bf16 [16.78,33.55MB) P fp32 [33.55MB..)
  // FINAL kernel writes all of d_out -> its input t12 lives in d_ws.
  unsigned short* A = (unsigned short*)d_out;
  unsigned short* B = A + 8388608;
  float* P = (float*)((char*)d_out + 33554432);

  // workspace layout (bytes)
  char* wsb = (char*)d_ws;
  unsigned short* wtb = (unsigned short*)wsb;          // 5,971,968 elems bf16
  const size_t o11 = 0,        o12 = 2359296, o21 = 3538944, o22 = 4128768,
               o23 = 4718592,  o24 = 5308416, o31 = 5603328, o32 = 5750784,
               o33 = 5898240;
  unsigned short* f2c = (unsigned short*)(wsb + 11943936);   // 2,097,152 elems
  unsigned* cbits = (unsigned*)(wsb + 16138240);
  unsigned* sbits = (unsigned*)(wsb + 16203776);
  float* cstp = (float*)(wsb + 16269312);                    // 4*24*512
  float* sstp = (float*)(wsb + 16465920);                    // 4*24*512
  float* gstp = (float*)(wsb + 16662528);                    // 4*3*512
  float* scal = (float*)(wsb + 16687104);
  float* shft = (float*)(wsb + 16703488);
  float* flagc = (float*)(wsb + 16719872);
  float* sany  = (float*)(wsb + 16719904);
  unsigned short* t12 = (unsigned short*)wsb;  // overlaps consumed Wt buffers

  const int NC = 512;

  wt_prep<<<(512 * 64 + 255) / 256, 256, 0, stream>>>(w11, wtb + o11, 512, 512);
  wt_prep<<<(256 * 64 + 255) / 256, 256, 0, stream>>>(w12, wtb + o12, 512, 256);
  wt_prep<<<(256 * 32 + 255) / 256, 256, 0, stream>>>(w21, wtb + o21, 256, 256);
  wt_prep<<<(256 * 32 + 255) / 256, 256, 0, stream>>>(w22, wtb + o22, 256, 256);
  wt_prep<<<(256 * 32 + 255) / 256, 256, 0, stream>>>(w23, wtb + o23, 256, 256);
  wt_prep<<<(128 * 32 + 255) / 256, 256, 0, stream>>>(w24, wtb + o24, 256, 128);
  wt_prep<<<(128 * 16 + 255) / 256, 256, 0, stream>>>(w31, wtb + o31, 128, 128);
  wt_prep<<<(128 * 16 + 255) / 256, 256, 0, stream>>>(w32, wtb + o32, 128, 128);
  wt_prep<<<( 64 * 16 + 255) / 256, 256, 0, stream>>>(w33, wtb + o33, 128,  64);

  nchw_to_nc8<<<(262144 + 255) / 256, 256, 0, stream>>>(f2, f2c, 64, 1024, 262144);

  pack_masks<<<64, 256, 0, stream>>>(cmask, smask, cbits, sbits);
  mask_flags<<<8, 1024, 0, stream>>>(cmask, smask, flagc, sany);

  // conv chain: 32x32 layers on proven kernel; 64/128-res layers on w128
  launch_conv(f2c, wtb + o11, b11, A, P, 512, 512, 32, 32, 4, stream);
  launch_conv(A,   wtb + o12, b12, B, P, 512, 256, 32, 32, 8, stream);
  unpool_shift_nc8<<<(524288 + 255) / 256, 256, 0, stream>>>(B, s2lh, s2hl, s2hh, A, 32, 32, 32, 524288);
  launch_conv_w128(A, wtb + o21, b21, B, P, 256, 256, 64, 64, 2, stream);
  launch_conv_w128(B, wtb + o22, b22, A, P, 256, 256, 64, 64, 2, stream);
  launch_conv_w128(A, wtb + o23, b23, B, P, 256, 256, 64, 64, 2, stream);
  launch_conv_w128(B, wtb + o24, b24, A, P, 256, 128, 64, 64, 4, stream);
  unpool_shift_nc8<<<(1048576 + 255) / 256, 256, 0, stream>>>(A, s1lh, s1hl, s1hh, B, 16, 64, 64, 1048576);

  // AdaIN: content=B (bf16), style=f1 (fp32) -> A
  masked_stats_bf16<<<dim3(512, 4), 256, 0, stream>>>(B, cbits, cstp, NC);
  masked_stats_f32g<<<dim3(512, 4), 256, 0, stream>>>(f1, sbits, sstp, gstp, NC);
  finalize_ss<<<16, 256, 0, stream>>>(cstp, sstp, gstp, flagc, sany, scal, shft, NC);
  adain_apply_nc8<<<dim3(64, 16), 256, 0, stream>>>(B, cbits, scal, shft, A);

  launch_conv_w128(A, wtb + o31, b31, B, P, 128, 128, 128, 128, 1, stream);
  launch_conv_w128(B, wtb + o32, b32, A, P, 128, 128, 128, 128, 1, stream);
  launch_conv(A, wtb + o33, b33, t12, P, 128, 64, 128, 128, 2, stream);

  // final: pair-vectorized unpool + rpad, reads t12 (d_ws) -> all of d_out
  unpool_rpad_final_v2<<<dim3(131, 256), 256, 0, stream>>>(
      t12, s0lh, s0hl, s0hh, (float*)d_out);
}

// Round 12
// 565.736 us; speedup vs baseline: 1.0285x; 1.0285x over previous
//
#include <hip/hip_runtime.h>

#define EPSF 1e-5f

typedef __attribute__((ext_vector_type(8)))  short short8;
typedef __attribute__((ext_vector_type(4)))  float f32x4;
typedef __attribute__((ext_vector_type(16))) float f32x16;

__device__ __forceinline__ unsigned short f2bf(float f) {
  unsigned u = __builtin_bit_cast(unsigned, f);
  unsigned r = (u + 0x7FFFu + ((u >> 16) & 1u)) >> 16;   // RNE
  return (unsigned short)r;
}
__device__ __forceinline__ float bf2f(unsigned short h) {
  unsigned u = ((unsigned)h) << 16;
  return __builtin_bit_cast(float, u);
}

// ---------------------------------------------------------------------------
// Weight pre-transpose: W[K][C][3][3] fp32 -> Wt[tap][C/8][K][8] bf16
// ---------------------------------------------------------------------------
__global__ void wt_prep(const float* __restrict__ w, unsigned short* __restrict__ wt,
                        int C, int K) {
  int C8 = C >> 3;
  int idx = blockIdx.x * 256 + threadIdx.x;
  if (idx >= K * C8) return;
  int k = idx / C8, ch = idx - k * C8;
  const float* src = w + ((size_t)k * C + ch * 8) * 9;
#pragma unroll
  for (int tap = 0; tap < 9; ++tap) {
    short8 v;
#pragma unroll
    for (int cl = 0; cl < 8; ++cl) v[cl] = (short)f2bf(src[cl * 9 + tap]);
    *(short8*)(wt + ((size_t)(tap * C8 + ch) * K + k) * 8) = v;
  }
}

// ---------------------------------------------------------------------------
// fp32 NCHW -> bf16 NC8HW8
// ---------------------------------------------------------------------------
__global__ void nchw_to_nc8(const float* __restrict__ in, unsigned short* __restrict__ out,
                            int C8, int HW, int total) {
  int idx = blockIdx.x * 256 + threadIdx.x;
  if (idx >= total) return;
  int pix = idx % HW; int t = idx / HW; int ch = t % C8; int n = t / C8;
  const float* s = in + ((size_t)(n * C8 + ch) * 8) * HW + pix;
  short8 v;
#pragma unroll
  for (int cl = 0; cl < 8; ++cl) v[cl] = (short)f2bf(s[(size_t)cl * HW]);
  *(short8*)(out + (size_t)idx * 8) = v;
}

// ===========================================================================
// Conv kernel A (proven): wave = 64 kchans x 64 pix (mf=2). Used for the 32x32
// layers (L1/L2, need deep split-C) and L9 (K=64).
// ===========================================================================
__global__ __launch_bounds__(256) void conv3x3_mfma(
    const unsigned short* __restrict__ act, const unsigned short* __restrict__ wt,
    const float* __restrict__ bias, unsigned short* __restrict__ out,
    float* __restrict__ partial, int C, int K, int H, int W, int S) {
  const int C8 = C >> 3, K8 = K >> 3;
  const int HW = H * W;
  const int tid = threadIdx.x;
  const int lane = tid & 63, wid = tid >> 6;
  const int l31 = lane & 31, lhi = lane >> 5;
  const int w0 = blockIdx.x * 16, h0 = blockIdx.y * 16;
  const int kbn = K >> 6;
  int zz = blockIdx.z;
  const int sp = zz % S; zz /= S;
  const int kb = zz % kbn;
  const int n  = zz / kbn;
  const int k0 = kb * 64;

  __shared__ __align__(16) unsigned short smem[24576];  // 2 x 1536 slots x 16B
  __shared__ float sbias[64];
  if (tid < 64) sbias[tid] = bias[k0 + tid];

  int g16[6];
#pragma unroll
  for (int it = 0; it < 6; ++it) {
    int slot = it * 256 + wid * 64 + lane;
    int s = slot < 1296 ? slot : 0;
    int chi = s / 324; int r = s - chi * 324;
    int y = r / 18, x = r - y * 18;
    int gy = h0 - 1 + y; gy = gy < 0 ? -gy : (gy >= H ? 2 * H - 2 - gy : gy);
    int gx = w0 - 1 + x; gx = gx < 0 ? -gx : (gx >= W ? 2 * W - 2 - gx : gx);
    g16[it] = ((n * C8 + chi) * H + gy) * W + gx;
  }

  const int pbase = wid * 64;
  int pb[2];
#pragma unroll
  for (int nf = 0; nf < 2; ++nf) {
    int p = pbase + nf * 32 + l31;
    pb[nf] = (p >> 4) * 18 + (p & 15);
  }
  int bb8[2][2];
#pragma unroll
  for (int ks = 0; ks < 2; ++ks)
#pragma unroll
    for (int nf = 0; nf < 2; ++nf)
      bb8[ks][nf] = ((ks * 2 + lhi) * 324 + pb[nf]) * 8;

  const size_t tapStep   = (size_t)C8 * K * 8;
  const size_t chunkStep = (size_t)4 * K * 8;
  const int cps = (C >> 5) / S;
  const int c0 = sp * cps;
  const unsigned short* ap[2][2];
#pragma unroll
  for (int ks = 0; ks < 2; ++ks)
#pragma unroll
    for (int mf = 0; mf < 2; ++mf)
      ap[ks][mf] = wt + ((size_t)(c0 * 4) * K
                  + (size_t)((ks * 2 + lhi) * K + k0 + mf * 32 + l31)) * 8;

  f32x16 acc[2][2] = {};

#define STAGE(BSEL, CI)                                                          \
  {                                                                              \
    _Pragma("unroll")                                                            \
    for (int it = 0; it < 6; ++it) {                                             \
      const unsigned short* g = act + ((size_t)g16[it] + (size_t)(CI) * 4 * HW) * 8; \
      __builtin_amdgcn_global_load_lds(                                          \
          (const __attribute__((address_space(1))) unsigned int*)g,              \
          (__attribute__((address_space(3))) unsigned int*)                      \
              &smem[(BSEL) * 12288 + (it * 256 + wid * 64) * 8],                 \
          16, 0, 0);                                                             \
    }                                                                            \
  }

  STAGE(0, c0)

  for (int i = 0; i < cps; ++i) {
    __syncthreads();
    const int boff = (i & 1) * 12288;
    const unsigned short* aw[2][2];
    short8 acur[2][2], anx[2][2];
#pragma unroll
    for (int ks = 0; ks < 2; ++ks)
#pragma unroll
      for (int mf = 0; mf < 2; ++mf) {
        aw[ks][mf] = ap[ks][mf];
        acur[ks][mf] = *(const short8*)aw[ks][mf];
        aw[ks][mf] += tapStep;
      }
#pragma unroll
    for (int tap = 0; tap < 9; ++tap) {
      if (tap < 8) {
#pragma unroll
        for (int ks = 0; ks < 2; ++ks)
#pragma unroll
          for (int mf = 0; mf < 2; ++mf) {
            anx[ks][mf] = *(const short8*)aw[ks][mf];
            aw[ks][mf] += tapStep;
          }
      }
      if (tap == 7 && i + 1 < cps) STAGE((i & 1) ^ 1, c0 + i + 1)
      const int ty = tap / 3, txx = tap - ty * 3;
      const int toff = (ty * 18 + txx) * 8;
      short8 b[2][2];
#pragma unroll
      for (int ks = 0; ks < 2; ++ks)
#pragma unroll
        for (int nf = 0; nf < 2; ++nf)
          b[nf][ks] = *(const short8*)&smem[boff + bb8[ks][nf] + toff];
#pragma unroll
      for (int ks = 0; ks < 2; ++ks)
#pragma unroll
        for (int mf = 0; mf < 2; ++mf)
#pragma unroll
          for (int nf = 0; nf < 2; ++nf)
            acc[mf][nf] = __builtin_amdgcn_mfma_f32_32x32x16_bf16(
                acur[ks][mf], b[nf][ks], acc[mf][nf], 0, 0, 0);
#pragma unroll
      for (int ks = 0; ks < 2; ++ks)
#pragma unroll
        for (int mf = 0; mf < 2; ++mf)
          acur[ks][mf] = anx[ks][mf];
    }
#pragma unroll
    for (int ks = 0; ks < 2; ++ks)
#pragma unroll
      for (int mf = 0; mf < 2; ++mf)
        ap[ks][mf] += chunkStep;
  }

  if (S > 1) {
    float* P = partial + (size_t)sp * ((size_t)4 * K * HW);
#pragma unroll
    for (int mf = 0; mf < 2; ++mf)
#pragma unroll
      for (int nf = 0; nf < 2; ++nf) {
        int p = pbase + nf * 32 + l31;
        int gp = (h0 + (p >> 4)) * W + (w0 + (p & 15));
#pragma unroll
        for (int q = 0; q < 4; ++q) {
          size_t ad = ((size_t)(n * K8 + (k0 >> 3) + mf * 4 + q) * HW + gp) * 8 + 4 * lhi;
          f32x4 v = { acc[mf][nf][4 * q], acc[mf][nf][4 * q + 1],
                      acc[mf][nf][4 * q + 2], acc[mf][nf][4 * q + 3] };
          *(f32x4*)(P + ad) = v;
        }
      }
    return;
  }

  __syncthreads();
#pragma unroll
  for (int mf = 0; mf < 2; ++mf)
#pragma unroll
    for (int nf = 0; nf < 2; ++nf) {
      int pix = pbase + nf * 32 + l31;
#pragma unroll
      for (int rp = 0; rp < 8; ++rp) {
        const int r0 = rp * 2;
        int row0 = (r0 & 3) + 8 * (r0 >> 2) + 4 * lhi;
        int c64 = mf * 32 + row0;
        float v0 = acc[mf][nf][r0]     + sbias[c64];
        float v1 = acc[mf][nf][r0 + 1] + sbias[c64 + 1];
        v0 = v0 > 0.f ? v0 : 0.f;
        v1 = v1 > 0.f ? v1 : 0.f;
        unsigned pk = (unsigned)f2bf(v0) | ((unsigned)f2bf(v1) << 16);
        int chh = mf * 4 + (r0 >> 2);
        int clo = (r0 & 3) + 4 * lhi;
        *(unsigned*)&smem[((chh * 256 + pix) * 8 + clo)] = pk;
      }
    }
  __syncthreads();
#pragma unroll
  for (int i = 0; i < 8; ++i) {
    int slot = i * 256 + tid;
    int ch = slot >> 8;
    int p = slot & 255;
    int py = p >> 4, px = p & 15;
    short8 v = *(const short8*)&smem[slot * 8];
    *(short8*)(out + (((size_t)(n * K8 + (k0 >> 3) + ch) * H + h0 + py) * W + w0 + px) * 8) = v;
  }
#undef STAGE
}

// ===========================================================================
// Conv kernel B: wave = 128 kchans x 64 pix (mf=4), round-12: software
// pipeline — A-prefetch depth 1, STAGE after the chunk's last A-issue.
// ===========================================================================
__global__ __launch_bounds__(256) void conv3x3_mfma_w128(
    const unsigned short* __restrict__ act, const unsigned short* __restrict__ wt,
    const float* __restrict__ bias, unsigned short* __restrict__ out,
    float* __restrict__ partial, int C, int K, int H, int W, int S) {
  const int C8 = C >> 3, K8 = K >> 3;
  const int HW = H * W;
  const int tid = threadIdx.x;
  const int lane = tid & 63, wid = tid >> 6;
  const int l31 = lane & 31, lhi = lane >> 5;
  const int w0 = blockIdx.x * 16, h0 = blockIdx.y * 16;
  const int kbn = K >> 7;
  int zz = blockIdx.z;
  const int sp = zz % S; zz /= S;
  const int kb = zz % kbn;
  const int n  = zz / kbn;
  const int k0 = kb * 128;

  __shared__ __align__(16) unsigned short smem[24576];
  __shared__ float sbias[128];
  if (tid < 128) sbias[tid] = bias[k0 + tid];

  int g16[6];
#pragma unroll
  for (int it = 0; it < 6; ++it) {
    int slot = it * 256 + wid * 64 + lane;
    int s = slot < 1296 ? slot : 0;
    int chi = s / 324; int r = s - chi * 324;
    int y = r / 18, x = r - y * 18;
    int gy = h0 - 1 + y; gy = gy < 0 ? -gy : (gy >= H ? 2 * H - 2 - gy : gy);
    int gx = w0 - 1 + x; gx = gx < 0 ? -gx : (gx >= W ? 2 * W - 2 - gx : gx);
    g16[it] = ((n * C8 + chi) * H + gy) * W + gx;
  }

  const int pbase = wid * 64;
  int pb[2];
#pragma unroll
  for (int nf = 0; nf < 2; ++nf) {
    int p = pbase + nf * 32 + l31;
    pb[nf] = (p >> 4) * 18 + (p & 15);
  }
  int bb8[2][2];
#pragma unroll
  for (int ks = 0; ks < 2; ++ks)
#pragma unroll
    for (int nf = 0; nf < 2; ++nf)
      bb8[ks][nf] = ((ks * 2 + lhi) * 324 + pb[nf]) * 8;

  const size_t tapStep   = (size_t)C8 * K * 8;
  const size_t chunkStep = (size_t)4 * K * 8;
  const int cps = (C >> 5) / S;
  const int c0 = sp * cps;
  int aoff[2][4];
#pragma unroll
  for (int ks = 0; ks < 2; ++ks)
#pragma unroll
    for (int mf = 0; mf < 4; ++mf)
      aoff[ks][mf] = ((ks * 2 + lhi) * K + k0 + mf * 32 + l31) * 8;
  const unsigned short* abase = wt + (size_t)(c0 * 4) * K * 8;

  f32x16 acc[4][2] = {};

#define STAGE(BSEL, CI)                                                          \
  {                                                                              \
    _Pragma("unroll")                                                            \
    for (int it = 0; it < 6; ++it) {                                             \
      const unsigned short* g = act + ((size_t)g16[it] + (size_t)(CI) * 4 * HW) * 8; \
      __builtin_amdgcn_global_load_lds(                                          \
          (const __attribute__((address_space(1))) unsigned int*)g,              \
          (__attribute__((address_space(3))) unsigned int*)                      \
              &smem[(BSEL) * 12288 + (it * 256 + wid * 64) * 8],                 \
          16, 0, 0);                                                             \
    }                                                                            \
  }

  STAGE(0, c0)

  for (int i = 0; i < cps; ++i) {
    __syncthreads();
    const int boff = (i & 1) * 12288;
    const unsigned short* atap = abase + tapStep;   // tap-1 plane
    short8 acur[2][4], anx[2][4];
#pragma unroll
    for (int ks = 0; ks < 2; ++ks)
#pragma unroll
      for (int mf = 0; mf < 4; ++mf)
        acur[ks][mf] = *(const short8*)(abase + aoff[ks][mf]);   // tap 0
#pragma unroll
    for (int tap = 0; tap < 9; ++tap) {
      if (tap < 8) {                       // prefetch tap+1 A-fragments
#pragma unroll
        for (int ks = 0; ks < 2; ++ks)
#pragma unroll
          for (int mf = 0; mf < 4; ++mf)
            anx[ks][mf] = *(const short8*)(atap + aoff[ks][mf]);
        atap += tapStep;
      }
      // after the chunk's LAST A-issue -> A-waits never drain staging
      if (tap == 7 && i + 1 < cps) STAGE((i & 1) ^ 1, c0 + i + 1)
      const int ty = tap / 3, txx = tap - ty * 3;
      const int toff = (ty * 18 + txx) * 8;
      short8 b[2][2];
#pragma unroll
      for (int ks = 0; ks < 2; ++ks)
#pragma unroll
        for (int nf = 0; nf < 2; ++nf)
          b[nf][ks] = *(const short8*)&smem[boff + bb8[ks][nf] + toff];
#pragma unroll
      for (int ks = 0; ks < 2; ++ks)
#pragma unroll
        for (int mf = 0; mf < 4; ++mf)
#pragma unroll
          for (int nf = 0; nf < 2; ++nf)
            acc[mf][nf] = __builtin_amdgcn_mfma_f32_32x32x16_bf16(
                acur[ks][mf], b[nf][ks], acc[mf][nf], 0, 0, 0);
#pragma unroll
      for (int ks = 0; ks < 2; ++ks)
#pragma unroll
        for (int mf = 0; mf < 4; ++mf)
          acur[ks][mf] = anx[ks][mf];
    }
    abase += chunkStep;
  }

  if (S > 1) {
    float* P = partial + (size_t)sp * ((size_t)4 * K * HW);
#pragma unroll
    for (int mf = 0; mf < 4; ++mf)
#pragma unroll
      for (int nf = 0; nf < 2; ++nf) {
        int p = pbase + nf * 32 + l31;
        int gp = (h0 + (p >> 4)) * W + (w0 + (p & 15));
#pragma unroll
        for (int q = 0; q < 4; ++q) {
          size_t ad = ((size_t)(n * K8 + (k0 >> 3) + mf * 4 + q) * HW + gp) * 8 + 4 * lhi;
          f32x4 v = { acc[mf][nf][4 * q], acc[mf][nf][4 * q + 1],
                      acc[mf][nf][4 * q + 2], acc[mf][nf][4 * q + 3] };
          *(f32x4*)(P + ad) = v;
        }
      }
    return;
  }

  // S==1 epilogue: two 64-chan transpose passes through smem
#pragma unroll
  for (int half = 0; half < 2; ++half) {
    __syncthreads();
#pragma unroll
    for (int m2 = 0; m2 < 2; ++m2) {
      const int mf = half * 2 + m2;
#pragma unroll
      for (int nf = 0; nf < 2; ++nf) {
        int pix = pbase + nf * 32 + l31;
#pragma unroll
        for (int rp = 0; rp < 8; ++rp) {
          const int r0 = rp * 2;
          int row0 = (r0 & 3) + 8 * (r0 >> 2) + 4 * lhi;
          int cl = half * 64 + m2 * 32 + row0;
          float v0 = acc[mf][nf][r0]     + sbias[cl];
          float v1 = acc[mf][nf][r0 + 1] + sbias[cl + 1];
          v0 = v0 > 0.f ? v0 : 0.f;
          v1 = v1 > 0.f ? v1 : 0.f;
          unsigned pk = (unsigned)f2bf(v0) | ((unsigned)f2bf(v1) << 16);
          int chh = m2 * 4 + (r0 >> 2);
          int clo = (r0 & 3) + 4 * lhi;
          *(unsigned*)&smem[((chh * 256 + pix) * 8 + clo)] = pk;
        }
      }
    }
    __syncthreads();
#pragma unroll
    for (int i = 0; i < 8; ++i) {
      int slot = i * 256 + tid;
      int ch = slot >> 8;
      int p = slot & 255;
      int py = p >> 4, px = p & 15;
      short8 v = *(const short8*)&smem[slot * 8];
      *(short8*)(out + (((size_t)(n * K8 + (k0 >> 3) + half * 8 + ch) * H + h0 + py)
                        * W + w0 + px) * 8) = v;
    }
  }
#undef STAGE
}

// ---------------------------------------------------------------------------
// combine split-C partials: sum + bias + relu + pack bf16 NC8HW8
// ---------------------------------------------------------------------------
__global__ void combine_bias_relu(const float* __restrict__ P, const float* __restrict__ bias,
                                  unsigned short* __restrict__ out, int S, int K8, int HW,
                                  int total8) {
  int idx = blockIdx.x * 256 + threadIdx.x;
  if (idx >= total8) return;
  int k8 = (idx / HW) % K8;
  const float* p = P + (size_t)idx * 8;
  size_t stride = (size_t)total8 * 8;
  float v[8];
#pragma unroll
  for (int c = 0; c < 8; ++c) v[c] = p[c];
  for (int s = 1; s < S; ++s) {
#pragma unroll
    for (int c = 0; c < 8; ++c) v[c] += p[(size_t)s * stride + c];
  }
  short8 r;
#pragma unroll
  for (int c = 0; c < 8; ++c) {
    float x = v[c] + bias[k8 * 8 + c];
    x = x > 0.f ? x : 0.f;
    r[c] = (short)f2bf(x);
  }
  *(short8*)(out + (size_t)idx * 8) = r;
}

// ---------------------------------------------------------------------------
// Wavelet unpool fused with rpad(1)+crop shift, NC8HW8 bf16 ll / fp32 bands.
// ---------------------------------------------------------------------------
__global__ void unpool_shift_nc8(const unsigned short* __restrict__ ll,
                                 const float* __restrict__ lh, const float* __restrict__ hl,
                                 const float* __restrict__ hh, unsigned short* __restrict__ out,
                                 int C8, int Hh, int Wh, int total) {
  int idx = blockIdx.x * 256 + threadIdx.x;
  if (idx >= total) return;
  const int Ho = 2 * Hh, Wo = 2 * Wh;
  int j = idx % Wo; int t = idx / Wo;
  int i = t % Ho; t /= Ho;
  int ch = t % C8; int n = t / C8;
  int si = (i == 0) ? 1 : i - 1;
  int sj = (j == 0) ? 1 : j - 1;
  float sa = (si & 1) ? 1.f : -1.f;
  float sb = (sj & 1) ? 1.f : -1.f;
  int hy = si >> 1, hx = sj >> 1;
  size_t HWh = (size_t)Hh * Wh;
  const unsigned short* lp = ll + ((size_t)(n * C8 + ch) * HWh + hy * Wh + hx) * 8;
  size_t bb = ((size_t)(n * C8 + ch) * 8 * Hh + hy) * Wh + hx;
  short8 res;
#pragma unroll
  for (int cl = 0; cl < 8; ++cl) {
    float v = 0.5f * (bf2f(lp[cl]) + sb * lh[bb + cl * HWh] + sa * hl[bb + cl * HWh]
                      + sa * sb * hh[bb + cl * HWh]);
    res[cl] = (short)f2bf(v);
  }
  *(short8*)(out + (size_t)idx * 8) = res;
}

// ---------------------------------------------------------------------------
// Final unpool + rpad, pair-vectorized: ll = t12 (bf16 NC8HW8, K=64),
// out fp32 NCHW (4,64,258,258). One thread per (img, row, col-pair).
// ---------------------------------------------------------------------------
__global__ void unpool_rpad_final_v2(const unsigned short* __restrict__ ll,
                                     const float* __restrict__ lh, const float* __restrict__ hl,
                                     const float* __restrict__ hh, float* __restrict__ out) {
  const int img = blockIdx.y;                 // n*64 + c
  int idx = blockIdx.x * 256 + threadIdx.x;   // over 258 rows * 129 pairs
  if (idx >= 258 * 129) return;
  int i = idx / 129, jm = idx - i * 129;
  const int n = img >> 6, c = img & 63;

  int si = (i == 0) ? 1 : i - 1; if (si >= 256) si = 254;
  float sa = (si & 1) ? 1.f : -1.f;
  int hy = si >> 1;
  int hx0 = (jm == 0) ? 0 : jm - 1;
  int hx1 = (jm == 128) ? 127 : jm;

  size_t lb = ((size_t)(n * 8 + (c >> 3)) * 16384 + hy * 128) * 8 + (c & 7);
  float lv0 = bf2f(ll[lb + hx0 * 8]);
  float lv1 = bf2f(ll[lb + hx1 * 8]);

  size_t bb = ((size_t)img * 128 + hy) * 128;
  float l0 = lh[bb + hx0], g0 = hl[bb + hx0], h0 = hh[bb + hx0];
  float l1 = lh[bb + hx1], g1 = hl[bb + hx1], h1 = hh[bb + hx1];
  float o0 = 0.5f * (lv0 + l0 + sa * (g0 + h0));
  float o1 = 0.5f * (lv1 - l1 + sa * (g1 - h1));
  float2 r = make_float2(o0, o1);
  *(float2*)&out[((size_t)img * 258 + i) * 258 + 2 * jm] = r;
}

// ---------------------------------------------------------------------------
// AdaIN support
// ---------------------------------------------------------------------------
__global__ void pack_masks(const float* __restrict__ cmask, const float* __restrict__ smask,
                           unsigned* __restrict__ cbits, unsigned* __restrict__ sbits) {
  int idx = blockIdx.x * 256 + threadIdx.x;
  if (idx >= 16384) return;
  int h = idx >> 7, w = idx & 127;
  unsigned cb = 0, sb = 0;
#pragma unroll
  for (int k = 0; k < 8; ++k) {
    int off = (k * 256 + 2 * h) * 256 + 2 * w;
    if (cmask[off] != 0.f) cb |= (1u << k);
    if (smask[off] != 0.f) sb |= (1u << k);
  }
  cbits[idx] = cb;
  sbits[idx] = sb;
}

__global__ __launch_bounds__(1024) void mask_flags(
    const float* __restrict__ cmask, const float* __restrict__ smask,
    float* __restrict__ flagc, float* __restrict__ sany) {
  int k = blockIdx.x;
  const float* cm = cmask + (size_t)k * 65536;
  const float* sm = smask + (size_t)k * 65536;
  int ca = 0, sa = 0;
  for (int i = threadIdx.x; i < 65536; i += 1024) {
    ca |= (cm[i] != 0.f);
    sa |= (sm[i] != 0.f);
  }
#pragma unroll
  for (int off = 32; off > 0; off >>= 1) {
    ca |= __shfl_xor(ca, off, 64);
    sa |= __shfl_xor(sa, off, 64);
  }
  __shared__ int rc[16], rs[16];
  int wv = threadIdx.x >> 6;
  if ((threadIdx.x & 63) == 0) { rc[wv] = ca; rs[wv] = sa; }
  __syncthreads();
  if (threadIdx.x == 0) {
    int c = 0, s = 0;
#pragma unroll
    for (int i = 0; i < 16; ++i) { c |= rc[i]; s |= rs[i]; }
    flagc[k] = c ? 1.f : 0.f;
    sany[k]  = s ? 1.f : 0.f;
  }
}

__global__ __launch_bounds__(256) void masked_stats_bf16(
    const unsigned short* __restrict__ feat, const unsigned* __restrict__ bits,
    float* __restrict__ outp, int NC) {
  constexpr int NV = 24;
  int b = blockIdx.x; int n = b >> 7, c = b & 127;
  const int sp = blockIdx.y;
  const unsigned short* f = feat + (size_t)(n * 16 + (c >> 3)) * 16384 * 8 + (c & 7);
  float acc[NV];
#pragma unroll
  for (int j = 0; j < NV; ++j) acc[j] = 0.f;
  const int p0 = sp * 4096;
  for (int it = 0; it < 16; ++it) {
    int i = p0 + it * 256 + threadIdx.x;
    float v = bf2f(f[(size_t)i * 8]) + EPSF;
    float nz = (v != 0.f) ? 1.f : 0.f;
    float v2 = v * v;
    unsigned m = bits[i];
#pragma unroll
    for (int k = 0; k < 8; ++k) {
      float mk = (float)((m >> k) & 1u);
      acc[k * 3 + 0] += mk * nz;
      acc[k * 3 + 1] += mk * v;
      acc[k * 3 + 2] += mk * v2;
    }
  }
#pragma unroll
  for (int j = 0; j < NV; ++j) {
    float v = acc[j];
#pragma unroll
    for (int off = 32; off > 0; off >>= 1) v += __shfl_xor(v, off, 64);
    acc[j] = v;
  }
  __shared__ float red[4][NV];
  int lane = threadIdx.x & 63, wv = threadIdx.x >> 6;
  if (lane == 0) {
#pragma unroll
    for (int j = 0; j < NV; ++j) red[wv][j] = acc[j];
  }
  __syncthreads();
  int tid = threadIdx.x;
  if (tid < NV) {
    float s = red[0][tid] + red[1][tid] + red[2][tid] + red[3][tid];
    outp[(sp * NV + tid) * NC + b] = s;
  }
}

__global__ __launch_bounds__(256) void masked_stats_f32g(
    const float* __restrict__ feat, const unsigned* __restrict__ bits,
    float* __restrict__ sstp, float* __restrict__ gstp, int NC) {
  constexpr int NV = 27;
  const int b = blockIdx.x;
  const int sp = blockIdx.y;
  const float* f = feat + (size_t)b * 16384;
  float acc[NV];
#pragma unroll
  for (int j = 0; j < NV; ++j) acc[j] = 0.f;
  const int p0 = sp * 4096;
#pragma unroll 1
  for (int it = 0; it < 4; ++it) {
    int p = p0 + it * 1024 + threadIdx.x * 4;
    float4 v4 = *(const float4*)&f[p];
    uint4 m4 = *(const uint4*)&bits[p];
#pragma unroll
    for (int e = 0; e < 4; ++e) {
      float v = (&v4.x)[e] + EPSF;
      unsigned m = (&m4.x)[e];
      float nz = (v != 0.f) ? 1.f : 0.f;
      float v2 = v * v;
#pragma unroll
      for (int k = 0; k < 8; ++k) {
        float mk = (float)((m >> k) & 1u);
        acc[k * 3 + 0] += mk * nz;
        acc[k * 3 + 1] += mk * v;
        acc[k * 3 + 2] += mk * v2;
      }
      acc[24] += nz; acc[25] += v; acc[26] += v2;
    }
  }
#pragma unroll
  for (int j = 0; j < NV; ++j) {
    float v = acc[j];
#pragma unroll
    for (int off = 32; off > 0; off >>= 1) v += __shfl_xor(v, off, 64);
    acc[j] = v;
  }
  __shared__ float red[4][NV];
  int lane = threadIdx.x & 63, wv = threadIdx.x >> 6;
  if (lane == 0) {
#pragma unroll
    for (int j = 0; j < NV; ++j) red[wv][j] = acc[j];
  }
  __syncthreads();
  int tid = threadIdx.x;
  if (tid < NV) {
    float s = red[0][tid] + red[1][tid] + red[2][tid] + red[3][tid];
    if (tid < 24) sstp[(sp * 24 + tid) * NC + b] = s;
    else gstp[(sp * 3 + (tid - 24)) * NC + b] = s;
  }
}

__global__ void finalize_ss(const float* __restrict__ cstp, const float* __restrict__ sstp,
                            const float* __restrict__ gstp, const float* __restrict__ flagc,
                            const float* __restrict__ sany,
                            float* __restrict__ scal, float* __restrict__ shft, int NC) {
  int idx = blockIdx.x * blockDim.x + threadIdx.x;
  if (idx >= 8 * NC) return;
  int k = idx / NC, b = idx - k * NC;
  bool useg = (sany[k] == 0.f);
  float ccnt = 0.f, cs1 = 0.f, cs2 = 0.f, scnt = 0.f, ss1 = 0.f, ss2 = 0.f;
#pragma unroll
  for (int s = 0; s < 4; ++s) {
    const float* cp = cstp + s * 24 * NC;
    ccnt += cp[(k * 3 + 0) * NC + b];
    cs1  += cp[(k * 3 + 1) * NC + b];
    cs2  += cp[(k * 3 + 2) * NC + b];
    if (useg) {
      const float* gp = gstp + s * 3 * NC;
      scnt += gp[0 * NC + b]; ss1 += gp[1 * NC + b]; ss2 += gp[2 * NC + b];
    } else {
      const float* spp = sstp + s * 24 * NC;
      scnt += spp[(k * 3 + 0) * NC + b];
      ss1  += spp[(k * 3 + 1) * NC + b];
      ss2  += spp[(k * 3 + 2) * NC + b];
    }
  }
  float cmn  = cs1 / fmaxf(ccnt, 1.f);
  float cvv  = (cs2 - ccnt * cmn * cmn) / fmaxf(ccnt - 1.f, 1.f) + EPSF;
  float cstd = sqrtf(cvv);
  float smn  = ss1 / fmaxf(scnt, 1.f);
  float svv  = (ss2 - scnt * smn * smn) / fmaxf(scnt - 1.f, 1.f) + EPSF;
  float sstd = sqrtf(svv);
  float fl = flagc[k];
  float r  = sstd / cstd;
  scal[idx] = fl * r;
  shft[idx] = fl * (smn - cmn * r);
}

__global__ void adain_apply_nc8(const unsigned short* __restrict__ content,
                                const unsigned* __restrict__ bits,
                                const float* __restrict__ scal, const float* __restrict__ shft,
                                unsigned short* __restrict__ out) {
  int ch = blockIdx.x & 15, n = blockIdx.x >> 4;
  __shared__ float ssc[8][8], ssh[8][8];
  if (threadIdx.x < 64) {
    int k = threadIdx.x >> 3, cl = threadIdx.x & 7;
    int c = ch * 8 + cl;
    ssc[k][cl] = scal[k * 512 + n * 128 + c];
    ssh[k][cl] = shft[k * 512 + n * 128 + c];
  }
  __syncthreads();
  const unsigned short* src = content + (size_t)blockIdx.x * 16384 * 8;
  unsigned short* dst = out + (size_t)blockIdx.x * 16384 * 8;
  const int p0 = blockIdx.y * 1024;
  for (int p = p0 + threadIdx.x; p < p0 + 1024; p += 256) {
    unsigned m = bits[p];
    float sc[8], sh[8];
#pragma unroll
    for (int cl = 0; cl < 8; ++cl) { sc[cl] = 0.f; sh[cl] = 0.f; }
    for (int k = 0; k < 8; ++k) {
      if ((m >> k) & 1u) {
#pragma unroll
        for (int cl = 0; cl < 8; ++cl) { sc[cl] += ssc[k][cl]; sh[cl] += ssh[k][cl]; }
      }
    }
    short8 v = *(const short8*)(src + (size_t)p * 8);
    short8 r;
#pragma unroll
    for (int cl = 0; cl < 8; ++cl) {
      float f = bf2f((unsigned short)v[cl]) + EPSF;
      r[cl] = (short)f2bf(f * sc[cl] + sh[cl]);
    }
    *(short8*)(dst + (size_t)p * 8) = r;
  }
}

// ---------------------------------------------------------------------------
static void launch_conv(const unsigned short* act, const unsigned short* wt,
                        const float* bias, unsigned short* out, float* partial,
                        int C, int K, int H, int W, int S, hipStream_t st) {
  dim3 g(W / 16, H / 16, 4 * (K / 64) * S);
  conv3x3_mfma<<<g, 256, 0, st>>>(act, wt, bias, out, partial, C, K, H, W, S);
  if (S > 1) {
    int total8 = 4 * (K >> 3) * H * W;
    combine_bias_relu<<<(total8 + 255) / 256, 256, 0, st>>>(
        partial, bias, out, S, K >> 3, H * W, total8);
  }
}

static void launch_conv_w128(const unsigned short* act, const unsigned short* wt,
                             const float* bias, unsigned short* out, float* partial,
                             int C, int K, int H, int W, int S, hipStream_t st) {
  dim3 g(W / 16, H / 16, 4 * (K / 128) * S);
  conv3x3_mfma_w128<<<g, 256, 0, st>>>(act, wt, bias, out, partial, C, K, H, W, S);
  if (S > 1) {
    int total8 = 4 * (K >> 3) * H * W;
    combine_bias_relu<<<(total8 + 255) / 256, 256, 0, st>>>(
        partial, bias, out, S, K >> 3, H * W, total8);
  }
}

extern "C" void kernel_launch(void* const* d_in, const int* in_sizes, int n_in,
                              void* d_out, int out_size, void* d_ws, size_t ws_size,
                              hipStream_t stream) {
  const float* f1   = (const float*)d_in[0];
  const float* f2   = (const float*)d_in[1];
  const float* s2lh = (const float*)d_in[2];
  const float* s2hl = (const float*)d_in[3];
  const float* s2hh = (const float*)d_in[4];
  const float* s1lh = (const float*)d_in[5];
  const float* s1hl = (const float*)d_in[6];
  const float* s1hh = (const float*)d_in[7];
  const float* s0lh = (const float*)d_in[8];
  const float* s0hl = (const float*)d_in[9];
  const float* s0hh = (const float*)d_in[10];
  const float* cmask = (const float*)d_in[11];
  const float* smask = (const float*)d_in[12];
  const float* w11 = (const float*)d_in[13]; const float* b11 = (const float*)d_in[14];
  const float* w12 = (const float*)d_in[15]; const float* b12 = (const float*)d_in[16];
  const float* w21 = (const float*)d_in[17]; const float* b21 = (const float*)d_in[18];
  const float* w22 = (const float*)d_in[19]; const float* b22 = (const float*)d_in[20];
  const float* w23 = (const float*)d_in[21]; const float* b23 = (const float*)d_in[22];
  const float* w24 = (const float*)d_in[23]; const float* b24 = (const float*)d_in[24];
  const float* w31 = (const float*)d_in[25]; const float* b31 = (const float*)d_in[26];
  const float* w32 = (const float*)d_in[27]; const float* b32 = (const float*)d_in[28];
  const float* w33 = (const float*)d_in[29]; const float* b33 = (const float*)d_in[30];

  // d_out layout: A bf16 [0,16.78MB) B bf16 [16.78,33.55MB) P fp32 [33.55MB..)
  // FINAL kernel writes all of d_out -> its input t12 lives in d_ws.
  unsigned short* A = (unsigned short*)d_out;
  unsigned short* B = A + 8388608;
  float* P = (float*)((char*)d_out + 33554432);

  // workspace layout (bytes)
  char* wsb = (char*)d_ws;
  unsigned short* wtb = (unsigned short*)wsb;          // 5,971,968 elems bf16
  const size_t o11 = 0,        o12 = 2359296, o21 = 3538944, o22 = 4128768,
               o23 = 4718592,  o24 = 5308416, o31 = 5603328, o32 = 5750784,
               o33 = 5898240;
  unsigned short* f2c = (unsigned short*)(wsb + 11943936);   // 2,097,152 elems
  unsigned* cbits = (unsigned*)(wsb + 16138240);
  unsigned* sbits = (unsigned*)(wsb + 16203776);
  float* cstp = (float*)(wsb + 16269312);                    // 4*24*512
  float* sstp = (float*)(wsb + 16465920);                    // 4*24*512
  float* gstp = (float*)(wsb + 16662528);                    // 4*3*512
  float* scal = (float*)(wsb + 16687104);
  float* shft = (float*)(wsb + 16703488);
  float* flagc = (float*)(wsb + 16719872);
  float* sany  = (float*)(wsb + 16719904);
  unsigned short* t12 = (unsigned short*)wsb;  // overlaps consumed Wt buffers

  const int NC = 512;

  wt_prep<<<(512 * 64 + 255) / 256, 256, 0, stream>>>(w11, wtb + o11, 512, 512);
  wt_prep<<<(256 * 64 + 255) / 256, 256, 0, stream>>>(w12, wtb + o12, 512, 256);
  wt_prep<<<(256 * 32 + 255) / 256, 256, 0, stream>>>(w21, wtb + o21, 256, 256);
  wt_prep<<<(256 * 32 + 255) / 256, 256, 0, stream>>>(w22, wtb + o22, 256, 256);
  wt_prep<<<(256 * 32 + 255) / 256, 256, 0, stream>>>(w23, wtb + o23, 256, 256);
  wt_prep<<<(128 * 32 + 255) / 256, 256, 0, stream>>>(w24, wtb + o24, 256, 128);
  wt_prep<<<(128 * 16 + 255) / 256, 256, 0, stream>>>(w31, wtb + o31, 128, 128);
  wt_prep<<<(128 * 16 + 255) / 256, 256, 0, stream>>>(w32, wtb + o32, 128, 128);
  wt_prep<<<( 64 * 16 + 255) / 256, 256, 0, stream>>>(w33, wtb + o33, 128,  64);

  nchw_to_nc8<<<(262144 + 255) / 256, 256, 0, stream>>>(f2, f2c, 64, 1024, 262144);

  pack_masks<<<64, 256, 0, stream>>>(cmask, smask, cbits, sbits);
  mask_flags<<<8, 1024, 0, stream>>>(cmask, smask, flagc, sany);

  // conv chain: 32x32 layers on proven kernel; 64/128-res layers on w128
  launch_conv(f2c, wtb + o11, b11, A, P, 512, 512, 32, 32, 4, stream);
  launch_conv(A,   wtb + o12, b12, B, P, 512, 256, 32, 32, 8, stream);
  unpool_shift_nc8<<<(524288 + 255) / 256, 256, 0, stream>>>(B, s2lh, s2hl, s2hh, A, 32, 32, 32, 524288);
  launch_conv_w128(A, wtb + o21, b21, B, P, 256, 256, 64, 64, 2, stream);
  launch_conv_w128(B, wtb + o22, b22, A, P, 256, 256, 64, 64, 2, stream);
  launch_conv_w128(A, wtb + o23, b23, B, P, 256, 256, 64, 64, 2, stream);
  launch_conv_w128(B, wtb + o24, b24, A, P, 256, 128, 64, 64, 4, stream);
  unpool_shift_nc8<<<(1048576 + 255) / 256, 256, 0, stream>>>(A, s1lh, s1hl, s1hh, B, 16, 64, 64, 1048576);

  // AdaIN: content=B (bf16), style=f1 (fp32) -> A
  masked_stats_bf16<<<dim3(512, 4), 256, 0, stream>>>(B, cbits, cstp, NC);
  masked_stats_f32g<<<dim3(512, 4), 256, 0, stream>>>(f1, sbits, sstp, gstp, NC);
  finalize_ss<<<16, 256, 0, stream>>>(cstp, sstp, gstp, flagc, sany, scal, shft, NC);
  adain_apply_nc8<<<dim3(64, 16), 256, 0, stream>>>(B, cbits, scal, shft, A);

  launch_conv_w128(A, wtb + o31, b31, B, P, 128, 128, 128, 128, 1, stream);
  launch_conv_w128(B, wtb + o32, b32, A, P, 128, 128, 128, 128, 1, stream);
  launch_conv(A, wtb + o33, b33, t12, P, 128, 64, 128, 128, 2, stream);

  // final: pair-vectorized unpool + rpad, reads t12 (d_ws) -> all of d_out
  unpool_rpad_final_v2<<<dim3(131, 256), 256, 0, stream>>>(
      t12, s0lh, s0hl, s0hh, (float*)d_out);
}

// Round 13
// 489.799 us; speedup vs baseline: 1.1879x; 1.1550x over previous
//
#include <hip/hip_runtime.h>

#define EPSF 1e-5f

typedef __attribute__((ext_vector_type(4)))  short short4v;
typedef __attribute__((ext_vector_type(8)))  short short8;
typedef __attribute__((ext_vector_type(4)))  float f32x4;
typedef __attribute__((ext_vector_type(16))) float f32x16;

__device__ __forceinline__ unsigned short f2bf(float f) {
  unsigned u = __builtin_bit_cast(unsigned, f);
  unsigned r = (u + 0x7FFFu + ((u >> 16) & 1u)) >> 16;   // RNE
  return (unsigned short)r;
}
__device__ __forceinline__ float bf2f(unsigned short h) {
  unsigned u = ((unsigned)h) << 16;
  return __builtin_bit_cast(float, u);
}

// ---------------------------------------------------------------------------
// Weight pre-transpose: W[K][C][3][3] fp32 -> Wt[tap][C/8][K][8] bf16
// ---------------------------------------------------------------------------
__global__ void wt_prep(const float* __restrict__ w, unsigned short* __restrict__ wt,
                        int C, int K) {
  int C8 = C >> 3;
  int idx = blockIdx.x * 256 + threadIdx.x;
  if (idx >= K * C8) return;
  int k = idx / C8, ch = idx - k * C8;
  const float* src = w + ((size_t)k * C + ch * 8) * 9;
#pragma unroll
  for (int tap = 0; tap < 9; ++tap) {
    short8 v;
#pragma unroll
    for (int cl = 0; cl < 8; ++cl) v[cl] = (short)f2bf(src[cl * 9 + tap]);
    *(short8*)(wt + ((size_t)(tap * C8 + ch) * K + k) * 8) = v;
  }
}

// ---------------------------------------------------------------------------
// fp32 NCHW -> bf16 NC8HW8
// ---------------------------------------------------------------------------
__global__ void nchw_to_nc8(const float* __restrict__ in, unsigned short* __restrict__ out,
                            int C8, int HW, int total) {
  int idx = blockIdx.x * 256 + threadIdx.x;
  if (idx >= total) return;
  int pix = idx % HW; int t = idx / HW; int ch = t % C8; int n = t / C8;
  const float* s = in + ((size_t)(n * C8 + ch) * 8) * HW + pix;
  short8 v;
#pragma unroll
  for (int cl = 0; cl < 8; ++cl) v[cl] = (short)f2bf(s[(size_t)cl * HW]);
  *(short8*)(out + (size_t)idx * 8) = v;
}

// ---------------------------------------------------------------------------
// Conv 3x3 reflect-pad, bf16 MFMA implicit GEMM, split-C + 2-phase prefetch.
// act: NC8HW8 bf16, wt: [9][C/8][K][8] bf16. Block: 4 waves, 64 k x 256 px.
// S>1 -> bf16 partials (NC8HW8 order, per-split stride 4*K*HW elements).
// ---------------------------------------------------------------------------
__global__ __launch_bounds__(256) void conv3x3_mfma(
    const unsigned short* __restrict__ act, const unsigned short* __restrict__ wt,
    const float* __restrict__ bias, unsigned short* __restrict__ out,
    unsigned short* __restrict__ partial, int C, int K, int H, int W, int S) {
  const int C8 = C >> 3, K8 = K >> 3;
  const int HW = H * W;
  const int tid = threadIdx.x;
  const int lane = tid & 63, wid = tid >> 6;
  const int l31 = lane & 31, lhi = lane >> 5;
  const int w0 = blockIdx.x * 16, h0 = blockIdx.y * 16;
  const int kbn = K >> 6;
  int zz = blockIdx.z;
  const int sp = zz % S; zz /= S;
  const int kb = zz % kbn;
  const int n  = zz / kbn;
  const int k0 = kb * 64;

  __shared__ __align__(16) unsigned short smem[24576];  // 2 x 1536 slots x 16B
  __shared__ float sbias[64];
  if (tid < 64) sbias[tid] = bias[k0 + tid];

  int g16[6];
#pragma unroll
  for (int it = 0; it < 6; ++it) {
    int slot = it * 256 + wid * 64 + lane;
    int s = slot < 1296 ? slot : 0;
    int chi = s / 324; int r = s - chi * 324;
    int y = r / 18, x = r - y * 18;
    int gy = h0 - 1 + y; gy = gy < 0 ? -gy : (gy >= H ? 2 * H - 2 - gy : gy);
    int gx = w0 - 1 + x; gx = gx < 0 ? -gx : (gx >= W ? 2 * W - 2 - gx : gx);
    g16[it] = ((n * C8 + chi) * H + gy) * W + gx;
  }

  const int pbase = wid * 64;
  int pb[2];
#pragma unroll
  for (int nf = 0; nf < 2; ++nf) {
    int p = pbase + nf * 32 + l31;
    pb[nf] = (p >> 4) * 18 + (p & 15);
  }
  int bb8[2][2];
#pragma unroll
  for (int ks = 0; ks < 2; ++ks)
#pragma unroll
    for (int nf = 0; nf < 2; ++nf)
      bb8[ks][nf] = ((ks * 2 + lhi) * 324 + pb[nf]) * 8;

  const size_t tapStep   = (size_t)C8 * K * 8;
  const size_t chunkStep = (size_t)4 * K * 8;
  const int cps = (C >> 5) / S;
  const int c0 = sp * cps;
  const unsigned short* ap[2][2];
#pragma unroll
  for (int ks = 0; ks < 2; ++ks)
#pragma unroll
    for (int mf = 0; mf < 2; ++mf)
      ap[ks][mf] = wt + ((size_t)(c0 * 4) * K
                  + (size_t)((ks * 2 + lhi) * K + k0 + mf * 32 + l31)) * 8;

  f32x16 acc[2][2] = {};

#define STAGE(BSEL, CI)                                                          \
  {                                                                              \
    _Pragma("unroll")                                                            \
    for (int it = 0; it < 6; ++it) {                                             \
      const unsigned short* g = act + ((size_t)g16[it] + (size_t)(CI) * 4 * HW) * 8; \
      __builtin_amdgcn_global_load_lds(                                          \
          (const __attribute__((address_space(1))) unsigned int*)g,              \
          (__attribute__((address_space(3))) unsigned int*)                      \
              &smem[(BSEL) * 12288 + (it * 256 + wid * 64) * 8],                 \
          16, 0, 0);                                                             \
    }                                                                            \
  }

  STAGE(0, c0)

  for (int i = 0; i < cps; ++i) {
    __syncthreads();
    const int boff = (i & 1) * 12288;
    const unsigned short* aw[2][2];
    short8 acur[2][2], anx[2][2];
#pragma unroll
    for (int ks = 0; ks < 2; ++ks)
#pragma unroll
      for (int mf = 0; mf < 2; ++mf) {
        aw[ks][mf] = ap[ks][mf];
        acur[ks][mf] = *(const short8*)aw[ks][mf];
        aw[ks][mf] += tapStep;
      }
#pragma unroll
    for (int tap = 0; tap < 9; ++tap) {
      if (tap < 8) {
#pragma unroll
        for (int ks = 0; ks < 2; ++ks)
#pragma unroll
          for (int mf = 0; mf < 2; ++mf) {
            anx[ks][mf] = *(const short8*)aw[ks][mf];
            aw[ks][mf] += tapStep;
          }
      }
      if (tap == 7 && i + 1 < cps) STAGE((i & 1) ^ 1, c0 + i + 1)
      const int ty = tap / 3, txx = tap - ty * 3;
      const int toff = (ty * 18 + txx) * 8;
      short8 b[2][2];
#pragma unroll
      for (int ks = 0; ks < 2; ++ks)
#pragma unroll
        for (int nf = 0; nf < 2; ++nf)
          b[nf][ks] = *(const short8*)&smem[boff + bb8[ks][nf] + toff];
#pragma unroll
      for (int ks = 0; ks < 2; ++ks)
#pragma unroll
        for (int mf = 0; mf < 2; ++mf)
#pragma unroll
          for (int nf = 0; nf < 2; ++nf)
            acc[mf][nf] = __builtin_amdgcn_mfma_f32_32x32x16_bf16(
                acur[ks][mf], b[nf][ks], acc[mf][nf], 0, 0, 0);
#pragma unroll
      for (int ks = 0; ks < 2; ++ks)
#pragma unroll
        for (int mf = 0; mf < 2; ++mf)
          acur[ks][mf] = anx[ks][mf];
    }
#pragma unroll
    for (int ks = 0; ks < 2; ++ks)
#pragma unroll
      for (int mf = 0; mf < 2; ++mf)
        ap[ks][mf] += chunkStep;
  }

  if (S > 1) {
    // bf16 partial write, NC8HW8 ordering; pixel is GLOBAL (h0/w0 applied).
    unsigned short* P = partial + (size_t)sp * ((size_t)4 * K * HW);
#pragma unroll
    for (int mf = 0; mf < 2; ++mf)
#pragma unroll
      for (int nf = 0; nf < 2; ++nf) {
        int p = pbase + nf * 32 + l31;
        int gp = (h0 + (p >> 4)) * W + (w0 + (p & 15));
#pragma unroll
        for (int q = 0; q < 4; ++q) {
          size_t ad = ((size_t)(n * K8 + (k0 >> 3) + mf * 4 + q) * HW + gp) * 8 + 4 * lhi;
          short4v v = { (short)f2bf(acc[mf][nf][4 * q]),
                        (short)f2bf(acc[mf][nf][4 * q + 1]),
                        (short)f2bf(acc[mf][nf][4 * q + 2]),
                        (short)f2bf(acc[mf][nf][4 * q + 3]) };
          *(short4v*)(P + ad) = v;
        }
      }
    return;
  }

  // S==1 epilogue: bias + relu + pack bf16 via LDS transpose
  __syncthreads();
#pragma unroll
  for (int mf = 0; mf < 2; ++mf)
#pragma unroll
    for (int nf = 0; nf < 2; ++nf) {
      int pix = pbase + nf * 32 + l31;
#pragma unroll
      for (int rp = 0; rp < 8; ++rp) {
        const int r0 = rp * 2;
        int row0 = (r0 & 3) + 8 * (r0 >> 2) + 4 * lhi;
        int c64 = mf * 32 + row0;
        float v0 = acc[mf][nf][r0]     + sbias[c64];
        float v1 = acc[mf][nf][r0 + 1] + sbias[c64 + 1];
        v0 = v0 > 0.f ? v0 : 0.f;
        v1 = v1 > 0.f ? v1 : 0.f;
        unsigned pk = (unsigned)f2bf(v0) | ((unsigned)f2bf(v1) << 16);
        int chh = mf * 4 + (r0 >> 2);
        int clo = (r0 & 3) + 4 * lhi;
        *(unsigned*)&smem[((chh * 256 + pix) * 8 + clo)] = pk;
      }
    }
  __syncthreads();
#pragma unroll
  for (int i = 0; i < 8; ++i) {
    int slot = i * 256 + tid;
    int ch = slot >> 8;
    int p = slot & 255;
    int py = p >> 4, px = p & 15;
    short8 v = *(const short8*)&smem[slot * 8];
    *(short8*)(out + (((size_t)(n * K8 + (k0 >> 3) + ch) * H + h0 + py) * W + w0 + px) * 8) = v;
  }
#undef STAGE
}

// ---------------------------------------------------------------------------
// combine bf16 split-C partials: sum(fp32) + bias + relu + pack bf16 NC8HW8
// ---------------------------------------------------------------------------
__global__ void combine_bias_relu(const unsigned short* __restrict__ P,
                                  const float* __restrict__ bias,
                                  unsigned short* __restrict__ out, int S, int K8, int HW,
                                  int total8) {
  int idx = blockIdx.x * 256 + threadIdx.x;
  if (idx >= total8) return;
  int k8 = (idx / HW) % K8;
  const unsigned short* p = P + (size_t)idx * 8;
  size_t stride = (size_t)total8 * 8;
  float v[8];
#pragma unroll
  for (int c = 0; c < 8; ++c) v[c] = bf2f(p[c]);
  for (int s = 1; s < S; ++s) {
#pragma unroll
    for (int c = 0; c < 8; ++c) v[c] += bf2f(p[(size_t)s * stride + c]);
  }
  short8 r;
#pragma unroll
  for (int c = 0; c < 8; ++c) {
    float x = v[c] + bias[k8 * 8 + c];
    x = x > 0.f ? x : 0.f;
    r[c] = (short)f2bf(x);
  }
  *(short8*)(out + (size_t)idx * 8) = r;
}

// ---------------------------------------------------------------------------
// Wavelet unpool fused with rpad(1)+crop shift, NC8HW8 bf16 ll / fp32 bands.
// ---------------------------------------------------------------------------
__global__ void unpool_shift_nc8(const unsigned short* __restrict__ ll,
                                 const float* __restrict__ lh, const float* __restrict__ hl,
                                 const float* __restrict__ hh, unsigned short* __restrict__ out,
                                 int C8, int Hh, int Wh, int total) {
  int idx = blockIdx.x * 256 + threadIdx.x;
  if (idx >= total) return;
  const int Ho = 2 * Hh, Wo = 2 * Wh;
  int j = idx % Wo; int t = idx / Wo;
  int i = t % Ho; t /= Ho;
  int ch = t % C8; int n = t / C8;
  int si = (i == 0) ? 1 : i - 1;
  int sj = (j == 0) ? 1 : j - 1;
  float sa = (si & 1) ? 1.f : -1.f;
  float sb = (sj & 1) ? 1.f : -1.f;
  int hy = si >> 1, hx = sj >> 1;
  size_t HWh = (size_t)Hh * Wh;
  const unsigned short* lp = ll + ((size_t)(n * C8 + ch) * HWh + hy * Wh + hx) * 8;
  size_t bb = ((size_t)(n * C8 + ch) * 8 * Hh + hy) * Wh + hx;
  short8 res;
#pragma unroll
  for (int cl = 0; cl < 8; ++cl) {
    float v = 0.5f * (bf2f(lp[cl]) + sb * lh[bb + cl * HWh] + sa * hl[bb + cl * HWh]
                      + sa * sb * hh[bb + cl * HWh]);
    res[cl] = (short)f2bf(v);
  }
  *(short8*)(out + (size_t)idx * 8) = res;
}

// ---------------------------------------------------------------------------
// Final unpool + rpad, pair-vectorized: ll = t12 (bf16 NC8HW8, K=64),
// out fp32 NCHW (4,64,258,258). One thread per (img, row, col-pair).
// ---------------------------------------------------------------------------
__global__ void unpool_rpad_final_v2(const unsigned short* __restrict__ ll,
                                     const float* __restrict__ lh, const float* __restrict__ hl,
                                     const float* __restrict__ hh, float* __restrict__ out) {
  const int img = blockIdx.y;                 // n*64 + c
  int idx = blockIdx.x * 256 + threadIdx.x;   // over 258 rows * 129 pairs
  if (idx >= 258 * 129) return;
  int i = idx / 129, jm = idx - i * 129;
  const int n = img >> 6, c = img & 63;

  int si = (i == 0) ? 1 : i - 1; if (si >= 256) si = 254;
  float sa = (si & 1) ? 1.f : -1.f;
  int hy = si >> 1;
  int hx0 = (jm == 0) ? 0 : jm - 1;
  int hx1 = (jm == 128) ? 127 : jm;

  size_t lb = ((size_t)(n * 8 + (c >> 3)) * 16384 + hy * 128) * 8 + (c & 7);
  float lv0 = bf2f(ll[lb + hx0 * 8]);
  float lv1 = bf2f(ll[lb + hx1 * 8]);

  size_t bb = ((size_t)img * 128 + hy) * 128;
  float l0 = lh[bb + hx0], g0 = hl[bb + hx0], h0 = hh[bb + hx0];
  float l1 = lh[bb + hx1], g1 = hl[bb + hx1], h1 = hh[bb + hx1];
  float o0 = 0.5f * (lv0 + l0 + sa * (g0 + h0));
  float o1 = 0.5f * (lv1 - l1 + sa * (g1 - h1));
  float2 r = make_float2(o0, o1);
  *(float2*)&out[((size_t)img * 258 + i) * 258 + 2 * jm] = r;
}

// ---------------------------------------------------------------------------
// AdaIN support
// ---------------------------------------------------------------------------
__global__ void pack_masks(const float* __restrict__ cmask, const float* __restrict__ smask,
                           unsigned* __restrict__ cbits, unsigned* __restrict__ sbits) {
  int idx = blockIdx.x * 256 + threadIdx.x;
  if (idx >= 16384) return;
  int h = idx >> 7, w = idx & 127;
  unsigned cb = 0, sb = 0;
#pragma unroll
  for (int k = 0; k < 8; ++k) {
    int off = (k * 256 + 2 * h) * 256 + 2 * w;
    if (cmask[off] != 0.f) cb |= (1u << k);
    if (smask[off] != 0.f) sb |= (1u << k);
  }
  cbits[idx] = cb;
  sbits[idx] = sb;
}

__global__ __launch_bounds__(1024) void mask_flags(
    const float* __restrict__ cmask, const float* __restrict__ smask,
    float* __restrict__ flagc, float* __restrict__ sany) {
  int k = blockIdx.x;
  const float* cm = cmask + (size_t)k * 65536;
  const float* sm = smask + (size_t)k * 65536;
  int ca = 0, sa = 0;
  for (int i = threadIdx.x; i < 65536; i += 1024) {
    ca |= (cm[i] != 0.f);
    sa |= (sm[i] != 0.f);
  }
#pragma unroll
  for (int off = 32; off > 0; off >>= 1) {
    ca |= __shfl_xor(ca, off, 64);
    sa |= __shfl_xor(sa, off, 64);
  }
  __shared__ int rc[16], rs[16];
  int wv = threadIdx.x >> 6;
  if ((threadIdx.x & 63) == 0) { rc[wv] = ca; rs[wv] = sa; }
  __syncthreads();
  if (threadIdx.x == 0) {
    int c = 0, s = 0;
#pragma unroll
    for (int i = 0; i < 16; ++i) { c |= rc[i]; s |= rs[i]; }
    flagc[k] = c ? 1.f : 0.f;
    sany[k]  = s ? 1.f : 0.f;
  }
}

__global__ __launch_bounds__(256) void masked_stats_bf16(
    const unsigned short* __restrict__ feat, const unsigned* __restrict__ bits,
    float* __restrict__ outp, int NC) {
  constexpr int NV = 24;
  int b = blockIdx.x; int n = b >> 7, c = b & 127;
  const int sp = blockIdx.y;
  const unsigned short* f = feat + (size_t)(n * 16 + (c >> 3)) * 16384 * 8 + (c & 7);
  float acc[NV];
#pragma unroll
  for (int j = 0; j < NV; ++j) acc[j] = 0.f;
  const int p0 = sp * 4096;
  for (int it = 0; it < 16; ++it) {
    int i = p0 + it * 256 + threadIdx.x;
    float v = bf2f(f[(size_t)i * 8]) + EPSF;
    float nz = (v != 0.f) ? 1.f : 0.f;
    float v2 = v * v;
    unsigned m = bits[i];
#pragma unroll
    for (int k = 0; k < 8; ++k) {
      float mk = (float)((m >> k) & 1u);
      acc[k * 3 + 0] += mk * nz;
      acc[k * 3 + 1] += mk * v;
      acc[k * 3 + 2] += mk * v2;
    }
  }
#pragma unroll
  for (int j = 0; j < NV; ++j) {
    float v = acc[j];
#pragma unroll
    for (int off = 32; off > 0; off >>= 1) v += __shfl_xor(v, off, 64);
    acc[j] = v;
  }
  __shared__ float red[4][NV];
  int lane = threadIdx.x & 63, wv = threadIdx.x >> 6;
  if (lane == 0) {
#pragma unroll
    for (int j = 0; j < NV; ++j) red[wv][j] = acc[j];
  }
  __syncthreads();
  int tid = threadIdx.x;
  if (tid < NV) {
    float s = red[0][tid] + red[1][tid] + red[2][tid] + red[3][tid];
    outp[(sp * NV + tid) * NC + b] = s;
  }
}

__global__ __launch_bounds__(256) void masked_stats_f32g(
    const float* __restrict__ feat, const unsigned* __restrict__ bits,
    float* __restrict__ sstp, float* __restrict__ gstp, int NC) {
  constexpr int NV = 27;
  const int b = blockIdx.x;
  const int sp = blockIdx.y;
  const float* f = feat + (size_t)b * 16384;
  float acc[NV];
#pragma unroll
  for (int j = 0; j < NV; ++j) acc[j] = 0.f;
  const int p0 = sp * 4096;
#pragma unroll 1
  for (int it = 0; it < 4; ++it) {
    int p = p0 + it * 1024 + threadIdx.x * 4;
    float4 v4 = *(const float4*)&f[p];
    uint4 m4 = *(const uint4*)&bits[p];
#pragma unroll
    for (int e = 0; e < 4; ++e) {
      float v = (&v4.x)[e] + EPSF;
      unsigned m = (&m4.x)[e];
      float nz = (v != 0.f) ? 1.f : 0.f;
      float v2 = v * v;
#pragma unroll
      for (int k = 0; k < 8; ++k) {
        float mk = (float)((m >> k) & 1u);
        acc[k * 3 + 0] += mk * nz;
        acc[k * 3 + 1] += mk * v;
        acc[k * 3 + 2] += mk * v2;
      }
      acc[24] += nz; acc[25] += v; acc[26] += v2;
    }
  }
#pragma unroll
  for (int j = 0; j < NV; ++j) {
    float v = acc[j];
#pragma unroll
    for (int off = 32; off > 0; off >>= 1) v += __shfl_xor(v, off, 64);
    acc[j] = v;
  }
  __shared__ float red[4][NV];
  int lane = threadIdx.x & 63, wv = threadIdx.x >> 6;
  if (lane == 0) {
#pragma unroll
    for (int j = 0; j < NV; ++j) red[wv][j] = acc[j];
  }
  __syncthreads();
  int tid = threadIdx.x;
  if (tid < NV) {
    float s = red[0][tid] + red[1][tid] + red[2][tid] + red[3][tid];
    if (tid < 24) sstp[(sp * 24 + tid) * NC + b] = s;
    else gstp[(sp * 3 + (tid - 24)) * NC + b] = s;
  }
}

__global__ void finalize_ss(const float* __restrict__ cstp, const float* __restrict__ sstp,
                            const float* __restrict__ gstp, const float* __restrict__ flagc,
                            const float* __restrict__ sany,
                            float* __restrict__ scal, float* __restrict__ shft, int NC) {
  int idx = blockIdx.x * blockDim.x + threadIdx.x;
  if (idx >= 8 * NC) return;
  int k = idx / NC, b = idx - k * NC;
  bool useg = (sany[k] == 0.f);
  float ccnt = 0.f, cs1 = 0.f, cs2 = 0.f, scnt = 0.f, ss1 = 0.f, ss2 = 0.f;
#pragma unroll
  for (int s = 0; s < 4; ++s) {
    const float* cp = cstp + s * 24 * NC;
    ccnt += cp[(k * 3 + 0) * NC + b];
    cs1  += cp[(k * 3 + 1) * NC + b];
    cs2  += cp[(k * 3 + 2) * NC + b];
    if (useg) {
      const float* gp = gstp + s * 3 * NC;
      scnt += gp[0 * NC + b]; ss1 += gp[1 * NC + b]; ss2 += gp[2 * NC + b];
    } else {
      const float* spp = sstp + s * 24 * NC;
      scnt += spp[(k * 3 + 0) * NC + b];
      ss1  += spp[(k * 3 + 1) * NC + b];
      ss2  += spp[(k * 3 + 2) * NC + b];
    }
  }
  float cmn  = cs1 / fmaxf(ccnt, 1.f);
  float cvv  = (cs2 - ccnt * cmn * cmn) / fmaxf(ccnt - 1.f, 1.f) + EPSF;
  float cstd = sqrtf(cvv);
  float smn  = ss1 / fmaxf(scnt, 1.f);
  float svv  = (ss2 - scnt * smn * smn) / fmaxf(scnt - 1.f, 1.f) + EPSF;
  float sstd = sqrtf(svv);
  float fl = flagc[k];
  float r  = sstd / cstd;
  scal[idx] = fl * r;
  shft[idx] = fl * (smn - cmn * r);
}

__global__ void adain_apply_nc8(const unsigned short* __restrict__ content,
                                const unsigned* __restrict__ bits,
                                const float* __restrict__ scal, const float* __restrict__ shft,
                                unsigned short* __restrict__ out) {
  int ch = blockIdx.x & 15, n = blockIdx.x >> 4;
  __shared__ float ssc[8][8], ssh[8][8];
  if (threadIdx.x < 64) {
    int k = threadIdx.x >> 3, cl = threadIdx.x & 7;
    int c = ch * 8 + cl;
    ssc[k][cl] = scal[k * 512 + n * 128 + c];
    ssh[k][cl] = shft[k * 512 + n * 128 + c];
  }
  __syncthreads();
  const unsigned short* src = content + (size_t)blockIdx.x * 16384 * 8;
  unsigned short* dst = out + (size_t)blockIdx.x * 16384 * 8;
  const int p0 = blockIdx.y * 1024;
  for (int p = p0 + threadIdx.x; p < p0 + 1024; p += 256) {
    unsigned m = bits[p];
    float sc[8], sh[8];
#pragma unroll
    for (int cl = 0; cl < 8; ++cl) { sc[cl] = 0.f; sh[cl] = 0.f; }
    for (int k = 0; k < 8; ++k) {
      if ((m >> k) & 1u) {
#pragma unroll
        for (int cl = 0; cl < 8; ++cl) { sc[cl] += ssc[k][cl]; sh[cl] += ssh[k][cl]; }
      }
    }
    short8 v = *(const short8*)(src + (size_t)p * 8);
    short8 r;
#pragma unroll
    for (int cl = 0; cl < 8; ++cl) {
      float f = bf2f((unsigned short)v[cl]) + EPSF;
      r[cl] = (short)f2bf(f * sc[cl] + sh[cl]);
    }
    *(short8*)(dst + (size_t)p * 8) = r;
  }
}

// ---------------------------------------------------------------------------
static void launch_conv(const unsigned short* act, const unsigned short* wt,
                        const float* bias, unsigned short* out, unsigned short* partial,
                        int C, int K, int H, int W, int S, hipStream_t st) {
  dim3 g(W / 16, H / 16, 4 * (K / 64) * S);
  conv3x3_mfma<<<g, 256, 0, st>>>(act, wt, bias, out, partial, C, K, H, W, S);
  if (S > 1) {
    int total8 = 4 * (K >> 3) * H * W;
    combine_bias_relu<<<(total8 + 255) / 256, 256, 0, st>>>(
        partial, bias, out, S, K >> 3, H * W, total8);
  }
}

extern "C" void kernel_launch(void* const* d_in, const int* in_sizes, int n_in,
                              void* d_out, int out_size, void* d_ws, size_t ws_size,
                              hipStream_t stream) {
  const float* f1   = (const float*)d_in[0];
  const float* f2   = (const float*)d_in[1];
  const float* s2lh = (const float*)d_in[2];
  const float* s2hl = (const float*)d_in[3];
  const float* s2hh = (const float*)d_in[4];
  const float* s1lh = (const float*)d_in[5];
  const float* s1hl = (const float*)d_in[6];
  const float* s1hh = (const float*)d_in[7];
  const float* s0lh = (const float*)d_in[8];
  const float* s0hl = (const float*)d_in[9];
  const float* s0hh = (const float*)d_in[10];
  const float* cmask = (const float*)d_in[11];
  const float* smask = (const float*)d_in[12];
  const float* w11 = (const float*)d_in[13]; const float* b11 = (const float*)d_in[14];
  const float* w12 = (const float*)d_in[15]; const float* b12 = (const float*)d_in[16];
  const float* w21 = (const float*)d_in[17]; const float* b21 = (const float*)d_in[18];
  const float* w22 = (const float*)d_in[19]; const float* b22 = (const float*)d_in[20];
  const float* w23 = (const float*)d_in[21]; const float* b23 = (const float*)d_in[22];
  const float* w24 = (const float*)d_in[23]; const float* b24 = (const float*)d_in[24];
  const float* w31 = (const float*)d_in[25]; const float* b31 = (const float*)d_in[26];
  const float* w32 = (const float*)d_in[27]; const float* b32 = (const float*)d_in[28];
  const float* w33 = (const float*)d_in[29]; const float* b33 = (const float*)d_in[30];

  // d_out layout: A bf16 [0,16.78MB) B bf16 [16.78,33.55MB)
  //   P bf16 partials [33,554,432, 67,108,864) — every split config = exactly 32 MiB
  // FINAL kernel writes all of d_out -> its input t12 lives in d_ws.
  unsigned short* A = (unsigned short*)d_out;
  unsigned short* B = A + 8388608;
  unsigned short* P = (unsigned short*)((char*)d_out + 33554432);

  // workspace layout (bytes)
  char* wsb = (char*)d_ws;
  unsigned short* wtb = (unsigned short*)wsb;          // 5,971,968 elems bf16
  const size_t o11 = 0,        o12 = 2359296, o21 = 3538944, o22 = 4128768,
               o23 = 4718592,  o24 = 5308416, o31 = 5603328, o32 = 5750784,
               o33 = 5898240;
  unsigned short* f2c = (unsigned short*)(wsb + 11943936);   // 2,097,152 elems
  unsigned* cbits = (unsigned*)(wsb + 16138240);
  unsigned* sbits = (unsigned*)(wsb + 16203776);
  float* cstp = (float*)(wsb + 16269312);                    // 4*24*512
  float* sstp = (float*)(wsb + 16465920);                    // 4*24*512
  float* gstp = (float*)(wsb + 16662528);                    // 4*3*512
  float* scal = (float*)(wsb + 16687104);
  float* shft = (float*)(wsb + 16703488);
  float* flagc = (float*)(wsb + 16719872);
  float* sany  = (float*)(wsb + 16719904);
  unsigned short* t12 = (unsigned short*)wsb;  // overlaps consumed Wt buffers

  const int NC = 512;

  wt_prep<<<(512 * 64 + 255) / 256, 256, 0, stream>>>(w11, wtb + o11, 512, 512);
  wt_prep<<<(256 * 64 + 255) / 256, 256, 0, stream>>>(w12, wtb + o12, 512, 256);
  wt_prep<<<(256 * 32 + 255) / 256, 256, 0, stream>>>(w21, wtb + o21, 256, 256);
  wt_prep<<<(256 * 32 + 255) / 256, 256, 0, stream>>>(w22, wtb + o22, 256, 256);
  wt_prep<<<(256 * 32 + 255) / 256, 256, 0, stream>>>(w23, wtb + o23, 256, 256);
  wt_prep<<<(128 * 32 + 255) / 256, 256, 0, stream>>>(w24, wtb + o24, 256, 128);
  wt_prep<<<(128 * 16 + 255) / 256, 256, 0, stream>>>(w31, wtb + o31, 128, 128);
  wt_prep<<<(128 * 16 + 255) / 256, 256, 0, stream>>>(w32, wtb + o32, 128, 128);
  wt_prep<<<( 64 * 16 + 255) / 256, 256, 0, stream>>>(w33, wtb + o33, 128,  64);

  nchw_to_nc8<<<(262144 + 255) / 256, 256, 0, stream>>>(f2, f2c, 64, 1024, 262144);

  pack_masks<<<64, 256, 0, stream>>>(cmask, smask, cbits, sbits);
  mask_flags<<<8, 1024, 0, stream>>>(cmask, smask, flagc, sany);

  // conv chain (bf16 partials double every split; all layers >= 512 blocks,
  // most 1024):  L1 S=8, L2 S=16, L3-5 S=4, L6 S=8, L7/8 S=1, L9 S=4
  launch_conv(f2c, wtb + o11, b11, A, P, 512, 512, 32, 32, 8, stream);
  launch_conv(A,   wtb + o12, b12, B, P, 512, 256, 32, 32, 16, stream);
  unpool_shift_nc8<<<(524288 + 255) / 256, 256, 0, stream>>>(B, s2lh, s2hl, s2hh, A, 32, 32, 32, 524288);
  launch_conv(A,   wtb + o21, b21, B, P, 256, 256, 64, 64, 4, stream);
  launch_conv(B,   wtb + o22, b22, A, P, 256, 256, 64, 64, 4, stream);
  launch_conv(A,   wtb + o23, b23, B, P, 256, 256, 64, 64, 4, stream);
  launch_conv(B,   wtb + o24, b24, A, P, 256, 128, 64, 64, 8, stream);
  unpool_shift_nc8<<<(1048576 + 255) / 256, 256, 0, stream>>>(A, s1lh, s1hl, s1hh, B, 16, 64, 64, 1048576);

  // AdaIN: content=B (bf16), style=f1 (fp32) -> A
  masked_stats_bf16<<<dim3(512, 4), 256, 0, stream>>>(B, cbits, cstp, NC);
  masked_stats_f32g<<<dim3(512, 4), 256, 0, stream>>>(f1, sbits, sstp, gstp, NC);
  finalize_ss<<<16, 256, 0, stream>>>(cstp, sstp, gstp, flagc, sany, scal, shft, NC);
  adain_apply_nc8<<<dim3(64, 16), 256, 0, stream>>>(B, cbits, scal, shft, A);

  launch_conv(A, wtb + o31, b31, B, P, 128, 128, 128, 128, 1, stream);
  launch_conv(B, wtb + o32, b32, A, P, 128, 128, 128, 128, 1, stream);
  launch_conv(A, wtb + o33, b33, t12, P, 128, 64, 128, 128, 4, stream);

  // final: pair-vectorized unpool + rpad, reads t12 (d_ws) -> all of d_out
  unpool_rpad_final_v2<<<dim3(131, 256), 256, 0, stream>>>(
      t12, s0lh, s0hl, s0hh, (float*)d_out);
}

// Round 14
// 483.149 us; speedup vs baseline: 1.2043x; 1.0138x over previous
//
#include <hip/hip_runtime.h>

#define EPSF 1e-5f

typedef __attribute__((ext_vector_type(4)))  short short4v;
typedef __attribute__((ext_vector_type(8)))  short short8;
typedef __attribute__((ext_vector_type(4)))  float f32x4;
typedef __attribute__((ext_vector_type(16))) float f32x16;

__device__ __forceinline__ unsigned short f2bf(float f) {
  unsigned u = __builtin_bit_cast(unsigned, f);
  unsigned r = (u + 0x7FFFu + ((u >> 16) & 1u)) >> 16;   // RNE
  return (unsigned short)r;
}
__device__ __forceinline__ float bf2f(unsigned short h) {
  unsigned u = ((unsigned)h) << 16;
  return __builtin_bit_cast(float, u);
}

// ---------------------------------------------------------------------------
// Weight pre-transpose: W[K][C][3][3] fp32 -> Wt[tap][C/8][K][8] bf16
// blockIdx.y = tap (9-way parallel).
// ---------------------------------------------------------------------------
__global__ void wt_prep(const float* __restrict__ w, unsigned short* __restrict__ wt,
                        int C, int K) {
  int C8 = C >> 3;
  int idx = blockIdx.x * 256 + threadIdx.x;
  if (idx >= K * C8) return;
  int k = idx / C8, ch = idx - k * C8;
  int tap = blockIdx.y;
  const float* src = w + ((size_t)k * C + ch * 8) * 9 + tap;
  short8 v;
#pragma unroll
  for (int cl = 0; cl < 8; ++cl) v[cl] = (short)f2bf(src[cl * 9]);
  *(short8*)(wt + ((size_t)(tap * C8 + ch) * K + k) * 8) = v;
}

// ---------------------------------------------------------------------------
// fp32 NCHW -> bf16 NC8HW8
// ---------------------------------------------------------------------------
__global__ void nchw_to_nc8(const float* __restrict__ in, unsigned short* __restrict__ out,
                            int C8, int HW, int total) {
  int idx = blockIdx.x * 256 + threadIdx.x;
  if (idx >= total) return;
  int pix = idx % HW; int t = idx / HW; int ch = t % C8; int n = t / C8;
  const float* s = in + ((size_t)(n * C8 + ch) * 8) * HW + pix;
  short8 v;
#pragma unroll
  for (int cl = 0; cl < 8; ++cl) v[cl] = (short)f2bf(s[(size_t)cl * HW]);
  *(short8*)(out + (size_t)idx * 8) = v;
}

// ---------------------------------------------------------------------------
// Conv 3x3 reflect-pad, bf16 MFMA implicit GEMM, split-C + 2-phase prefetch.
// act: NC8HW8 bf16, wt: [9][C/8][K][8] bf16. Block: 4 waves, 64 k x 256 px.
// S>1 -> bf16 partials (NC8HW8 order, per-split stride 4*K*HW elements).
// ---------------------------------------------------------------------------
__global__ __launch_bounds__(256) void conv3x3_mfma(
    const unsigned short* __restrict__ act, const unsigned short* __restrict__ wt,
    const float* __restrict__ bias, unsigned short* __restrict__ out,
    unsigned short* __restrict__ partial, int C, int K, int H, int W, int S) {
  const int C8 = C >> 3, K8 = K >> 3;
  const int HW = H * W;
  const int tid = threadIdx.x;
  const int lane = tid & 63, wid = tid >> 6;
  const int l31 = lane & 31, lhi = lane >> 5;
  const int w0 = blockIdx.x * 16, h0 = blockIdx.y * 16;
  const int kbn = K >> 6;
  int zz = blockIdx.z;
  const int sp = zz % S; zz /= S;
  const int kb = zz % kbn;
  const int n  = zz / kbn;
  const int k0 = kb * 64;

  __shared__ __align__(16) unsigned short smem[24576];  // 2 x 1536 slots x 16B
  __shared__ float sbias[64];
  if (tid < 64) sbias[tid] = bias[k0 + tid];

  int g16[6];
#pragma unroll
  for (int it = 0; it < 6; ++it) {
    int slot = it * 256 + wid * 64 + lane;
    int s = slot < 1296 ? slot : 0;
    int chi = s / 324; int r = s - chi * 324;
    int y = r / 18, x = r - y * 18;
    int gy = h0 - 1 + y; gy = gy < 0 ? -gy : (gy >= H ? 2 * H - 2 - gy : gy);
    int gx = w0 - 1 + x; gx = gx < 0 ? -gx : (gx >= W ? 2 * W - 2 - gx : gx);
    g16[it] = ((n * C8 + chi) * H + gy) * W + gx;
  }

  const int pbase = wid * 64;
  int pb[2];
#pragma unroll
  for (int nf = 0; nf < 2; ++nf) {
    int p = pbase + nf * 32 + l31;
    pb[nf] = (p >> 4) * 18 + (p & 15);
  }
  int bb8[2][2];
#pragma unroll
  for (int ks = 0; ks < 2; ++ks)
#pragma unroll
    for (int nf = 0; nf < 2; ++nf)
      bb8[ks][nf] = ((ks * 2 + lhi) * 324 + pb[nf]) * 8;

  const size_t tapStep   = (size_t)C8 * K * 8;
  const size_t chunkStep = (size_t)4 * K * 8;
  const int cps = (C >> 5) / S;
  const int c0 = sp * cps;
  const unsigned short* ap[2][2];
#pragma unroll
  for (int ks = 0; ks < 2; ++ks)
#pragma unroll
    for (int mf = 0; mf < 2; ++mf)
      ap[ks][mf] = wt + ((size_t)(c0 * 4) * K
                  + (size_t)((ks * 2 + lhi) * K + k0 + mf * 32 + l31)) * 8;

  f32x16 acc[2][2] = {};

#define STAGE(BSEL, CI)                                                          \
  {                                                                              \
    _Pragma("unroll")                                                            \
    for (int it = 0; it < 6; ++it) {                                             \
      const unsigned short* g = act + ((size_t)g16[it] + (size_t)(CI) * 4 * HW) * 8; \
      __builtin_amdgcn_global_load_lds(                                          \
          (const __attribute__((address_space(1))) unsigned int*)g,              \
          (__attribute__((address_space(3))) unsigned int*)                      \
              &smem[(BSEL) * 12288 + (it * 256 + wid * 64) * 8],                 \
          16, 0, 0);                                                             \
    }                                                                            \
  }

  STAGE(0, c0)

  for (int i = 0; i < cps; ++i) {
    __syncthreads();
    const int boff = (i & 1) * 12288;
    const unsigned short* aw[2][2];
    short8 acur[2][2], anx[2][2];
#pragma unroll
    for (int ks = 0; ks < 2; ++ks)
#pragma unroll
      for (int mf = 0; mf < 2; ++mf) {
        aw[ks][mf] = ap[ks][mf];
        acur[ks][mf] = *(const short8*)aw[ks][mf];
        aw[ks][mf] += tapStep;
      }
#pragma unroll
    for (int tap = 0; tap < 9; ++tap) {
      if (tap < 8) {
#pragma unroll
        for (int ks = 0; ks < 2; ++ks)
#pragma unroll
          for (int mf = 0; mf < 2; ++mf) {
            anx[ks][mf] = *(const short8*)aw[ks][mf];
            aw[ks][mf] += tapStep;
          }
      }
      if (tap == 7 && i + 1 < cps) STAGE((i & 1) ^ 1, c0 + i + 1)
      const int ty = tap / 3, txx = tap - ty * 3;
      const int toff = (ty * 18 + txx) * 8;
      short8 b[2][2];
#pragma unroll
      for (int ks = 0; ks < 2; ++ks)
#pragma unroll
        for (int nf = 0; nf < 2; ++nf)
          b[nf][ks] = *(const short8*)&smem[boff + bb8[ks][nf] + toff];
#pragma unroll
      for (int ks = 0; ks < 2; ++ks)
#pragma unroll
        for (int mf = 0; mf < 2; ++mf)
#pragma unroll
          for (int nf = 0; nf < 2; ++nf)
            acc[mf][nf] = __builtin_amdgcn_mfma_f32_32x32x16_bf16(
                acur[ks][mf], b[nf][ks], acc[mf][nf], 0, 0, 0);
#pragma unroll
      for (int ks = 0; ks < 2; ++ks)
#pragma unroll
        for (int mf = 0; mf < 2; ++mf)
          acur[ks][mf] = anx[ks][mf];
    }
#pragma unroll
    for (int ks = 0; ks < 2; ++ks)
#pragma unroll
      for (int mf = 0; mf < 2; ++mf)
        ap[ks][mf] += chunkStep;
  }

  if (S > 1) {
    // bf16 partial write, NC8HW8 ordering; pixel is GLOBAL (h0/w0 applied).
    unsigned short* P = partial + (size_t)sp * ((size_t)4 * K * HW);
#pragma unroll
    for (int mf = 0; mf < 2; ++mf)
#pragma unroll
      for (int nf = 0; nf < 2; ++nf) {
        int p = pbase + nf * 32 + l31;
        int gp = (h0 + (p >> 4)) * W + (w0 + (p & 15));
#pragma unroll
        for (int q = 0; q < 4; ++q) {
          size_t ad = ((size_t)(n * K8 + (k0 >> 3) + mf * 4 + q) * HW + gp) * 8 + 4 * lhi;
          short4v v = { (short)f2bf(acc[mf][nf][4 * q]),
                        (short)f2bf(acc[mf][nf][4 * q + 1]),
                        (short)f2bf(acc[mf][nf][4 * q + 2]),
                        (short)f2bf(acc[mf][nf][4 * q + 3]) };
          *(short4v*)(P + ad) = v;
        }
      }
    return;
  }

  // S==1 epilogue: bias + relu + pack bf16 via LDS transpose
  __syncthreads();
#pragma unroll
  for (int mf = 0; mf < 2; ++mf)
#pragma unroll
    for (int nf = 0; nf < 2; ++nf) {
      int pix = pbase + nf * 32 + l31;
#pragma unroll
      for (int rp = 0; rp < 8; ++rp) {
        const int r0 = rp * 2;
        int row0 = (r0 & 3) + 8 * (r0 >> 2) + 4 * lhi;
        int c64 = mf * 32 + row0;
        float v0 = acc[mf][nf][r0]     + sbias[c64];
        float v1 = acc[mf][nf][r0 + 1] + sbias[c64 + 1];
        v0 = v0 > 0.f ? v0 : 0.f;
        v1 = v1 > 0.f ? v1 : 0.f;
        unsigned pk = (unsigned)f2bf(v0) | ((unsigned)f2bf(v1) << 16);
        int chh = mf * 4 + (r0 >> 2);
        int clo = (r0 & 3) + 4 * lhi;
        *(unsigned*)&smem[((chh * 256 + pix) * 8 + clo)] = pk;
      }
    }
  __syncthreads();
#pragma unroll
  for (int i = 0; i < 8; ++i) {
    int slot = i * 256 + tid;
    int ch = slot >> 8;
    int p = slot & 255;
    int py = p >> 4, px = p & 15;
    short8 v = *(const short8*)&smem[slot * 8];
    *(short8*)(out + (((size_t)(n * K8 + (k0 >> 3) + ch) * H + h0 + py) * W + w0 + px) * 8) = v;
  }
#undef STAGE
}

// ---------------------------------------------------------------------------
// combine bf16 split-C partials: sum(fp32) + bias + relu + pack bf16 NC8HW8
// ---------------------------------------------------------------------------
__global__ void combine_bias_relu(const unsigned short* __restrict__ P,
                                  const float* __restrict__ bias,
                                  unsigned short* __restrict__ out, int S, int K8, int HW,
                                  int total8) {
  int idx = blockIdx.x * 256 + threadIdx.x;
  if (idx >= total8) return;
  int k8 = (idx / HW) % K8;
  const unsigned short* p = P + (size_t)idx * 8;
  size_t stride = (size_t)total8 * 8;
  float v[8];
#pragma unroll
  for (int c = 0; c < 8; ++c) v[c] = bf2f(p[c]);
  for (int s = 1; s < S; ++s) {
#pragma unroll
    for (int c = 0; c < 8; ++c) v[c] += bf2f(p[(size_t)s * stride + c]);
  }
  short8 r;
#pragma unroll
  for (int c = 0; c < 8; ++c) {
    float x = v[c] + bias[k8 * 8 + c];
    x = x > 0.f ? x : 0.f;
    r[c] = (short)f2bf(x);
  }
  *(short8*)(out + (size_t)idx * 8) = r;
}

// ---------------------------------------------------------------------------
// FUSED: S-way bf16 partial sum + bias + ReLU (conv output "ll") + wavelet
// unpool + rpad(1)+crop shift. P at conv res Hh x Wh, out NC8HW8 2Hh x 2Wh.
// ---------------------------------------------------------------------------
__global__ void unpool_shift_fused(const unsigned short* __restrict__ P,
                                   const float* __restrict__ bias,
                                   const float* __restrict__ lh, const float* __restrict__ hl,
                                   const float* __restrict__ hh, unsigned short* __restrict__ out,
                                   int C8, int Hh, int Wh, int S, int total) {
  int idx = blockIdx.x * 256 + threadIdx.x;
  if (idx >= total) return;
  const int Ho = 2 * Hh, Wo = 2 * Wh;
  int j = idx % Wo; int t = idx / Wo;
  int i = t % Ho; t /= Ho;
  int ch = t % C8; int n = t / C8;
  int si = (i == 0) ? 1 : i - 1;
  int sj = (j == 0) ? 1 : j - 1;
  float sa = (si & 1) ? 1.f : -1.f;
  float sb = (sj & 1) ? 1.f : -1.f;
  int hy = si >> 1, hx = sj >> 1;
  size_t HWh = (size_t)Hh * Wh;
  const size_t sstr = (size_t)4 * (C8 * 8) * HWh;       // elems per split
  size_t lbase = ((size_t)(n * C8 + ch) * HWh + hy * Wh + hx) * 8;
  float ll[8];
  {
    short8 v0 = *(const short8*)(P + lbase);
#pragma unroll
    for (int cl = 0; cl < 8; ++cl) ll[cl] = bf2f((unsigned short)v0[cl]);
  }
  for (int s = 1; s < S; ++s) {
    short8 vs = *(const short8*)(P + (size_t)s * sstr + lbase);
#pragma unroll
    for (int cl = 0; cl < 8; ++cl) ll[cl] += bf2f((unsigned short)vs[cl]);
  }
#pragma unroll
  for (int cl = 0; cl < 8; ++cl) {
    float x = ll[cl] + bias[ch * 8 + cl];
    ll[cl] = x > 0.f ? x : 0.f;
  }
  size_t bb = ((size_t)(n * C8 + ch) * 8 * Hh + hy) * Wh + hx;
  short8 res;
#pragma unroll
  for (int cl = 0; cl < 8; ++cl) {
    float v = 0.5f * (ll[cl] + sb * lh[bb + cl * HWh] + sa * hl[bb + cl * HWh]
                      + sa * sb * hh[bb + cl * HWh]);
    res[cl] = (short)f2bf(v);
  }
  *(short8*)(out + (size_t)idx * 8) = res;
}

// ---------------------------------------------------------------------------
// Final unpool + rpad, pair-vectorized: ll = t12 (bf16 NC8HW8, K=64),
// out fp32 NCHW (4,64,258,258). One thread per (img, row, col-pair).
// ---------------------------------------------------------------------------
__global__ void unpool_rpad_final_v2(const unsigned short* __restrict__ ll,
                                     const float* __restrict__ lh, const float* __restrict__ hl,
                                     const float* __restrict__ hh, float* __restrict__ out) {
  const int img = blockIdx.y;                 // n*64 + c
  int idx = blockIdx.x * 256 + threadIdx.x;   // over 258 rows * 129 pairs
  if (idx >= 258 * 129) return;
  int i = idx / 129, jm = idx - i * 129;
  const int n = img >> 6, c = img & 63;

  int si = (i == 0) ? 1 : i - 1; if (si >= 256) si = 254;
  float sa = (si & 1) ? 1.f : -1.f;
  int hy = si >> 1;
  int hx0 = (jm == 0) ? 0 : jm - 1;
  int hx1 = (jm == 128) ? 127 : jm;

  size_t lb = ((size_t)(n * 8 + (c >> 3)) * 16384 + hy * 128) * 8 + (c & 7);
  float lv0 = bf2f(ll[lb + hx0 * 8]);
  float lv1 = bf2f(ll[lb + hx1 * 8]);

  size_t bb = ((size_t)img * 128 + hy) * 128;
  float l0 = lh[bb + hx0], g0 = hl[bb + hx0], h0 = hh[bb + hx0];
  float l1 = lh[bb + hx1], g1 = hl[bb + hx1], h1 = hh[bb + hx1];
  float o0 = 0.5f * (lv0 + l0 + sa * (g0 + h0));
  float o1 = 0.5f * (lv1 - l1 + sa * (g1 - h1));
  float2 r = make_float2(o0, o1);
  *(float2*)&out[((size_t)img * 258 + i) * 258 + 2 * jm] = r;
}

// ---------------------------------------------------------------------------
// AdaIN support
// ---------------------------------------------------------------------------
__global__ void pack_masks(const float* __restrict__ cmask, const float* __restrict__ smask,
                           unsigned* __restrict__ cbits, unsigned* __restrict__ sbits) {
  int idx = blockIdx.x * 256 + threadIdx.x;
  if (idx >= 16384) return;
  int h = idx >> 7, w = idx & 127;
  unsigned cb = 0, sb = 0;
#pragma unroll
  for (int k = 0; k < 8; ++k) {
    int off = (k * 256 + 2 * h) * 256 + 2 * w;
    if (cmask[off] != 0.f) cb |= (1u << k);
    if (smask[off] != 0.f) sb |= (1u << k);
  }
  cbits[idx] = cb;
  sbits[idx] = sb;
}

__global__ __launch_bounds__(1024) void mask_flags(
    const float* __restrict__ cmask, const float* __restrict__ smask,
    float* __restrict__ flagc, float* __restrict__ sany) {
  int k = blockIdx.x;
  const float* cm = cmask + (size_t)k * 65536;
  const float* sm = smask + (size_t)k * 65536;
  int ca = 0, sa = 0;
  for (int i = threadIdx.x; i < 65536; i += 1024) {
    ca |= (cm[i] != 0.f);
    sa |= (sm[i] != 0.f);
  }
#pragma unroll
  for (int off = 32; off > 0; off >>= 1) {
    ca |= __shfl_xor(ca, off, 64);
    sa |= __shfl_xor(sa, off, 64);
  }
  __shared__ int rc[16], rs[16];
  int wv = threadIdx.x >> 6;
  if ((threadIdx.x & 63) == 0) { rc[wv] = ca; rs[wv] = sa; }
  __syncthreads();
  if (threadIdx.x == 0) {
    int c = 0, s = 0;
#pragma unroll
    for (int i = 0; i < 16; ++i) { c |= rc[i]; s |= rs[i]; }
    flagc[k] = c ? 1.f : 0.f;
    sany[k]  = s ? 1.f : 0.f;
  }
}

__global__ __launch_bounds__(256) void masked_stats_bf16(
    const unsigned short* __restrict__ feat, const unsigned* __restrict__ bits,
    float* __restrict__ outp, int NC) {
  constexpr int NV = 24;
  int b = blockIdx.x; int n = b >> 7, c = b & 127;
  const int sp = blockIdx.y;
  const unsigned short* f = feat + (size_t)(n * 16 + (c >> 3)) * 16384 * 8 + (c & 7);
  float acc[NV];
#pragma unroll
  for (int j = 0; j < NV; ++j) acc[j] = 0.f;
  const int p0 = sp * 4096;
  for (int it = 0; it < 16; ++it) {
    int i = p0 + it * 256 + threadIdx.x;
    float v = bf2f(f[(size_t)i * 8]) + EPSF;
    float nz = (v != 0.f) ? 1.f : 0.f;
    float v2 = v * v;
    unsigned m = bits[i];
#pragma unroll
    for (int k = 0; k < 8; ++k) {
      float mk = (float)((m >> k) & 1u);
      acc[k * 3 + 0] += mk * nz;
      acc[k * 3 + 1] += mk * v;
      acc[k * 3 + 2] += mk * v2;
    }
  }
#pragma unroll
  for (int j = 0; j < NV; ++j) {
    float v = acc[j];
#pragma unroll
    for (int off = 32; off > 0; off >>= 1) v += __shfl_xor(v, off, 64);
    acc[j] = v;
  }
  __shared__ float red[4][NV];
  int lane = threadIdx.x & 63, wv = threadIdx.x >> 6;
  if (lane == 0) {
#pragma unroll
    for (int j = 0; j < NV; ++j) red[wv][j] = acc[j];
  }
  __syncthreads();
  int tid = threadIdx.x;
  if (tid < NV) {
    float s = red[0][tid] + red[1][tid] + red[2][tid] + red[3][tid];
    outp[(sp * NV + tid) * NC + b] = s;
  }
}

__global__ __launch_bounds__(256) void masked_stats_f32g(
    const float* __restrict__ feat, const unsigned* __restrict__ bits,
    float* __restrict__ sstp, float* __restrict__ gstp, int NC) {
  constexpr int NV = 27;
  const int b = blockIdx.x;
  const int sp = blockIdx.y;
  const float* f = feat + (size_t)b * 16384;
  float acc[NV];
#pragma unroll
  for (int j = 0; j < NV; ++j) acc[j] = 0.f;
  const int p0 = sp * 4096;
#pragma unroll 1
  for (int it = 0; it < 4; ++it) {
    int p = p0 + it * 1024 + threadIdx.x * 4;
    float4 v4 = *(const float4*)&f[p];
    uint4 m4 = *(const uint4*)&bits[p];
#pragma unroll
    for (int e = 0; e < 4; ++e) {
      float v = (&v4.x)[e] + EPSF;
      unsigned m = (&m4.x)[e];
      float nz = (v != 0.f) ? 1.f : 0.f;
      float v2 = v * v;
#pragma unroll
      for (int k = 0; k < 8; ++k) {
        float mk = (float)((m >> k) & 1u);
        acc[k * 3 + 0] += mk * nz;
        acc[k * 3 + 1] += mk * v;
        acc[k * 3 + 2] += mk * v2;
      }
      acc[24] += nz; acc[25] += v; acc[26] += v2;
    }
  }
#pragma unroll
  for (int j = 0; j < NV; ++j) {
    float v = acc[j];
#pragma unroll
    for (int off = 32; off > 0; off >>= 1) v += __shfl_xor(v, off, 64);
    acc[j] = v;
  }
  __shared__ float red[4][NV];
  int lane = threadIdx.x & 63, wv = threadIdx.x >> 6;
  if (lane == 0) {
#pragma unroll
    for (int j = 0; j < NV; ++j) red[wv][j] = acc[j];
  }
  __syncthreads();
  int tid = threadIdx.x;
  if (tid < NV) {
    float s = red[0][tid] + red[1][tid] + red[2][tid] + red[3][tid];
    if (tid < 24) sstp[(sp * 24 + tid) * NC + b] = s;
    else gstp[(sp * 3 + (tid - 24)) * NC + b] = s;
  }
}

__global__ void finalize_ss(const float* __restrict__ cstp, const float* __restrict__ sstp,
                            const float* __restrict__ gstp, const float* __restrict__ flagc,
                            const float* __restrict__ sany,
                            float* __restrict__ scal, float* __restrict__ shft, int NC) {
  int idx = blockIdx.x * blockDim.x + threadIdx.x;
  if (idx >= 8 * NC) return;
  int k = idx / NC, b = idx - k * NC;
  bool useg = (sany[k] == 0.f);
  float ccnt = 0.f, cs1 = 0.f, cs2 = 0.f, scnt = 0.f, ss1 = 0.f, ss2 = 0.f;
#pragma unroll
  for (int s = 0; s < 4; ++s) {
    const float* cp = cstp + s * 24 * NC;
    ccnt += cp[(k * 3 + 0) * NC + b];
    cs1  += cp[(k * 3 + 1) * NC + b];
    cs2  += cp[(k * 3 + 2) * NC + b];
    if (useg) {
      const float* gp = gstp + s * 3 * NC;
      scnt += gp[0 * NC + b]; ss1 += gp[1 * NC + b]; ss2 += gp[2 * NC + b];
    } else {
      const float* spp = sstp + s * 24 * NC;
      scnt += spp[(k * 3 + 0) * NC + b];
      ss1  += spp[(k * 3 + 1) * NC + b];
      ss2  += spp[(k * 3 + 2) * NC + b];
    }
  }
  float cmn  = cs1 / fmaxf(ccnt, 1.f);
  float cvv  = (cs2 - ccnt * cmn * cmn) / fmaxf(ccnt - 1.f, 1.f) + EPSF;
  float cstd = sqrtf(cvv);
  float smn  = ss1 / fmaxf(scnt, 1.f);
  float svv  = (ss2 - scnt * smn * smn) / fmaxf(scnt - 1.f, 1.f) + EPSF;
  float sstd = sqrtf(svv);
  float fl = flagc[k];
  float r  = sstd / cstd;
  scal[idx] = fl * r;
  shft[idx] = fl * (smn - cmn * r);
}

__global__ void adain_apply_nc8(const unsigned short* __restrict__ content,
                                const unsigned* __restrict__ bits,
                                const float* __restrict__ scal, const float* __restrict__ shft,
                                unsigned short* __restrict__ out) {
  int ch = blockIdx.x & 15, n = blockIdx.x >> 4;
  __shared__ float ssc[8][8], ssh[8][8];
  if (threadIdx.x < 64) {
    int k = threadIdx.x >> 3, cl = threadIdx.x & 7;
    int c = ch * 8 + cl;
    ssc[k][cl] = scal[k * 512 + n * 128 + c];
    ssh[k][cl] = shft[k * 512 + n * 128 + c];
  }
  __syncthreads();
  const unsigned short* src = content + (size_t)blockIdx.x * 16384 * 8;
  unsigned short* dst = out + (size_t)blockIdx.x * 16384 * 8;
  const int p0 = blockIdx.y * 1024;
  for (int p = p0 + threadIdx.x; p < p0 + 1024; p += 256) {
    unsigned m = bits[p];
    float sc[8], sh[8];
#pragma unroll
    for (int cl = 0; cl < 8; ++cl) { sc[cl] = 0.f; sh[cl] = 0.f; }
    for (int k = 0; k < 8; ++k) {
      if ((m >> k) & 1u) {
#pragma unroll
        for (int cl = 0; cl < 8; ++cl) { sc[cl] += ssc[k][cl]; sh[cl] += ssh[k][cl]; }
      }
    }
    short8 v = *(const short8*)(src + (size_t)p * 8);
    short8 r;
#pragma unroll
    for (int cl = 0; cl < 8; ++cl) {
      float f = bf2f((unsigned short)v[cl]) + EPSF;
      r[cl] = (short)f2bf(f * sc[cl] + sh[cl]);
    }
    *(short8*)(dst + (size_t)p * 8) = r;
  }
}

// ---------------------------------------------------------------------------
static void launch_conv(const unsigned short* act, const unsigned short* wt,
                        const float* bias, unsigned short* out, unsigned short* partial,
                        int C, int K, int H, int W, int S, bool combine, hipStream_t st) {
  dim3 g(W / 16, H / 16, 4 * (K / 64) * S);
  conv3x3_mfma<<<g, 256, 0, st>>>(act, wt, bias, out, partial, C, K, H, W, S);
  if (S > 1 && combine) {
    int total8 = 4 * (K >> 3) * H * W;
    combine_bias_relu<<<(total8 + 255) / 256, 256, 0, st>>>(
        partial, bias, out, S, K >> 3, H * W, total8);
  }
}

extern "C" void kernel_launch(void* const* d_in, const int* in_sizes, int n_in,
                              void* d_out, int out_size, void* d_ws, size_t ws_size,
                              hipStream_t stream) {
  const float* f1   = (const float*)d_in[0];
  const float* f2   = (const float*)d_in[1];
  const float* s2lh = (const float*)d_in[2];
  const float* s2hl = (const float*)d_in[3];
  const float* s2hh = (const float*)d_in[4];
  const float* s1lh = (const float*)d_in[5];
  const float* s1hl = (const float*)d_in[6];
  const float* s1hh = (const float*)d_in[7];
  const float* s0lh = (const float*)d_in[8];
  const float* s0hl = (const float*)d_in[9];
  const float* s0hh = (const float*)d_in[10];
  const float* cmask = (const float*)d_in[11];
  const float* smask = (const float*)d_in[12];
  const float* w11 = (const float*)d_in[13]; const float* b11 = (const float*)d_in[14];
  const float* w12 = (const float*)d_in[15]; const float* b12 = (const float*)d_in[16];
  const float* w21 = (const float*)d_in[17]; const float* b21 = (const float*)d_in[18];
  const float* w22 = (const float*)d_in[19]; const float* b22 = (const float*)d_in[20];
  const float* w23 = (const float*)d_in[21]; const float* b23 = (const float*)d_in[22];
  const float* w24 = (const float*)d_in[23]; const float* b24 = (const float*)d_in[24];
  const float* w31 = (const float*)d_in[25]; const float* b31 = (const float*)d_in[26];
  const float* w32 = (const float*)d_in[27]; const float* b32 = (const float*)d_in[28];
  const float* w33 = (const float*)d_in[29]; const float* b33 = (const float*)d_in[30];

  // d_out layout: A bf16 [0,16.78MB) B bf16 [16.78,33.55MB)
  //   P bf16 partials [33,554,432, 67,108,864)
  // FINAL kernel writes all of d_out -> its input t12 lives in d_ws.
  unsigned short* A = (unsigned short*)d_out;
  unsigned short* B = A + 8388608;
  unsigned short* P = (unsigned short*)((char*)d_out + 33554432);

  // workspace layout (bytes)
  char* wsb = (char*)d_ws;
  unsigned short* wtb = (unsigned short*)wsb;          // 5,971,968 elems bf16
  const size_t o11 = 0,        o12 = 2359296, o21 = 3538944, o22 = 4128768,
               o23 = 4718592,  o24 = 5308416, o31 = 5603328, o32 = 5750784,
               o33 = 5898240;
  unsigned short* f2c = (unsigned short*)(wsb + 11943936);   // 2,097,152 elems
  unsigned* cbits = (unsigned*)(wsb + 16138240);
  unsigned* sbits = (unsigned*)(wsb + 16203776);
  float* cstp = (float*)(wsb + 16269312);                    // 4*24*512
  float* sstp = (float*)(wsb + 16465920);                    // 4*24*512
  float* gstp = (float*)(wsb + 16662528);                    // 4*3*512
  float* scal = (float*)(wsb + 16687104);
  float* shft = (float*)(wsb + 16703488);
  float* flagc = (float*)(wsb + 16719872);
  float* sany  = (float*)(wsb + 16719904);
  unsigned short* t12 = (unsigned short*)wsb;  // overlaps consumed Wt buffers

  const int NC = 512;

  wt_prep<<<dim3((512 * 64 + 255) / 256, 9), 256, 0, stream>>>(w11, wtb + o11, 512, 512);
  wt_prep<<<dim3((256 * 64 + 255) / 256, 9), 256, 0, stream>>>(w12, wtb + o12, 512, 256);
  wt_prep<<<dim3((256 * 32 + 255) / 256, 9), 256, 0, stream>>>(w21, wtb + o21, 256, 256);
  wt_prep<<<dim3((256 * 32 + 255) / 256, 9), 256, 0, stream>>>(w22, wtb + o22, 256, 256);
  wt_prep<<<dim3((256 * 32 + 255) / 256, 9), 256, 0, stream>>>(w23, wtb + o23, 256, 256);
  wt_prep<<<dim3((128 * 32 + 255) / 256, 9), 256, 0, stream>>>(w24, wtb + o24, 256, 128);
  wt_prep<<<dim3((128 * 16 + 255) / 256, 9), 256, 0, stream>>>(w31, wtb + o31, 128, 128);
  wt_prep<<<dim3((128 * 16 + 255) / 256, 9), 256, 0, stream>>>(w32, wtb + o32, 128, 128);
  wt_prep<<<dim3(( 64 * 16 + 255) / 256, 9), 256, 0, stream>>>(w33, wtb + o33, 128,  64);

  nchw_to_nc8<<<(262144 + 255) / 256, 256, 0, stream>>>(f2, f2c, 64, 1024, 262144);

  pack_masks<<<64, 256, 0, stream>>>(cmask, smask, cbits, sbits);
  mask_flags<<<8, 1024, 0, stream>>>(cmask, smask, flagc, sany);

  // conv chain: L1 S=8, L2 S=16 (combine fused into unpool), L3-5 S=4,
  // L6 S=8 (fused), L7/8 S=1, L9 S=4
  launch_conv(f2c, wtb + o11, b11, A, P, 512, 512, 32, 32, 8, true, stream);
  launch_conv(A,   wtb + o12, b12, B, P, 512, 256, 32, 32, 16, false, stream);
  unpool_shift_fused<<<(524288 + 255) / 256, 256, 0, stream>>>(
      P, b12, s2lh, s2hl, s2hh, A, 32, 32, 32, 16, 524288);
  launch_conv(A,   wtb + o21, b21, B, P, 256, 256, 64, 64, 4, true, stream);
  launch_conv(B,   wtb + o22, b22, A, P, 256, 256, 64, 64, 4, true, stream);
  launch_conv(A,   wtb + o23, b23, B, P, 256, 256, 64, 64, 4, true, stream);
  launch_conv(B,   wtb + o24, b24, A, P, 256, 128, 64, 64, 8, false, stream);
  unpool_shift_fused<<<(1048576 + 255) / 256, 256, 0, stream>>>(
      P, b24, s1lh, s1hl, s1hh, B, 16, 64, 64, 8, 1048576);

  // AdaIN: content=B (bf16), style=f1 (fp32) -> A
  masked_stats_bf16<<<dim3(512, 4), 256, 0, stream>>>(B, cbits, cstp, NC);
  masked_stats_f32g<<<dim3(512, 4), 256, 0, stream>>>(f1, sbits, sstp, gstp, NC);
  finalize_ss<<<16, 256, 0, stream>>>(cstp, sstp, gstp, flagc, sany, scal, shft, NC);
  adain_apply_nc8<<<dim3(64, 16), 256, 0, stream>>>(B, cbits, scal, shft, A);

  launch_conv(A, wtb + o31, b31, B, P, 128, 128, 128, 128, 1, true, stream);
  launch_conv(B, wtb + o32, b32, A, P, 128, 128, 128, 128, 1, true, stream);
  launch_conv(A, wtb + o33, b33, t12, P, 128, 64, 128, 128, 4, true, stream);

  // final: pair-vectorized unpool + rpad, reads t12 (d_ws) -> all of d_out
  unpool_rpad_final_v2<<<dim3(131, 256), 256, 0, stream>>>(
      t12, s0lh, s0hl, s0hh, (float*)d_out);
}

// Round 15
// 445.019 us; speedup vs baseline: 1.3075x; 1.0857x over previous
//
#include <hip/hip_runtime.h>

#define EPSF 1e-5f

typedef __attribute__((ext_vector_type(4)))  short short4v;
typedef __attribute__((ext_vector_type(8)))  short short8;
typedef __attribute__((ext_vector_type(4)))  float f32x4;
typedef __attribute__((ext_vector_type(16))) float f32x16;

__device__ __forceinline__ unsigned short f2bf(float f) {
  unsigned u = __builtin_bit_cast(unsigned, f);
  unsigned r = (u + 0x7FFFu + ((u >> 16) & 1u)) >> 16;   // RNE
  return (unsigned short)r;
}
__device__ __forceinline__ float bf2f(unsigned short h) {
  unsigned u = ((unsigned)h) << 16;
  return __builtin_bit_cast(float, u);
}

// ---------------------------------------------------------------------------
// Weight pre-transpose: W[K][C][3][3] fp32 -> Wt[tap][C/8][K][8] bf16
// blockIdx.y = tap (9-way parallel).
// ---------------------------------------------------------------------------
__global__ void wt_prep(const float* __restrict__ w, unsigned short* __restrict__ wt,
                        int C, int K) {
  int C8 = C >> 3;
  int idx = blockIdx.x * 256 + threadIdx.x;
  if (idx >= K * C8) return;
  int k = idx / C8, ch = idx - k * C8;
  int tap = blockIdx.y;
  const float* src = w + ((size_t)k * C + ch * 8) * 9 + tap;
  short8 v;
#pragma unroll
  for (int cl = 0; cl < 8; ++cl) v[cl] = (short)f2bf(src[cl * 9]);
  *(short8*)(wt + ((size_t)(tap * C8 + ch) * K + k) * 8) = v;
}

// ---------------------------------------------------------------------------
// fp32 NCHW -> bf16 NC8HW8
// ---------------------------------------------------------------------------
__global__ void nchw_to_nc8(const float* __restrict__ in, unsigned short* __restrict__ out,
                            int C8, int HW, int total) {
  int idx = blockIdx.x * 256 + threadIdx.x;
  if (idx >= total) return;
  int pix = idx % HW; int t = idx / HW; int ch = t % C8; int n = t / C8;
  const float* s = in + ((size_t)(n * C8 + ch) * 8) * HW + pix;
  short8 v;
#pragma unroll
  for (int cl = 0; cl < 8; ++cl) v[cl] = (short)f2bf(s[(size_t)cl * HW]);
  *(short8*)(out + (size_t)idx * 8) = v;
}

// ---------------------------------------------------------------------------
// Conv 3x3 reflect-pad, bf16 MFMA implicit GEMM, split-C + 2-phase prefetch.
// act: NC8HW8 bf16, wt: [9][C/8][K][8] bf16. Block: 4 waves, 64 k x 256 px.
// S>1 -> bf16 partials (NC8HW8 order, per-split stride 4*K*HW elements).
// ---------------------------------------------------------------------------
__global__ __launch_bounds__(256) void conv3x3_mfma(
    const unsigned short* __restrict__ act, const unsigned short* __restrict__ wt,
    const float* __restrict__ bias, unsigned short* __restrict__ out,
    unsigned short* __restrict__ partial, int C, int K, int H, int W, int S) {
  const int C8 = C >> 3, K8 = K >> 3;
  const int HW = H * W;
  const int tid = threadIdx.x;
  const int lane = tid & 63, wid = tid >> 6;
  const int l31 = lane & 31, lhi = lane >> 5;
  const int w0 = blockIdx.x * 16, h0 = blockIdx.y * 16;
  const int kbn = K >> 6;
  int zz = blockIdx.z;
  const int sp = zz % S; zz /= S;
  const int kb = zz % kbn;
  const int n  = zz / kbn;
  const int k0 = kb * 64;

  __shared__ __align__(16) unsigned short smem[24576];  // 2 x 1536 slots x 16B
  __shared__ float sbias[64];
  if (tid < 64) sbias[tid] = bias[k0 + tid];

  int g16[6];
#pragma unroll
  for (int it = 0; it < 6; ++it) {
    int slot = it * 256 + wid * 64 + lane;
    int s = slot < 1296 ? slot : 0;
    int chi = s / 324; int r = s - chi * 324;
    int y = r / 18, x = r - y * 18;
    int gy = h0 - 1 + y; gy = gy < 0 ? -gy : (gy >= H ? 2 * H - 2 - gy : gy);
    int gx = w0 - 1 + x; gx = gx < 0 ? -gx : (gx >= W ? 2 * W - 2 - gx : gx);
    g16[it] = ((n * C8 + chi) * H + gy) * W + gx;
  }

  const int pbase = wid * 64;
  int pb[2];
#pragma unroll
  for (int nf = 0; nf < 2; ++nf) {
    int p = pbase + nf * 32 + l31;
    pb[nf] = (p >> 4) * 18 + (p & 15);
  }
  int bb8[2][2];
#pragma unroll
  for (int ks = 0; ks < 2; ++ks)
#pragma unroll
    for (int nf = 0; nf < 2; ++nf)
      bb8[ks][nf] = ((ks * 2 + lhi) * 324 + pb[nf]) * 8;

  const size_t tapStep   = (size_t)C8 * K * 8;
  const size_t chunkStep = (size_t)4 * K * 8;
  const int cps = (C >> 5) / S;
  const int c0 = sp * cps;
  const unsigned short* ap[2][2];
#pragma unroll
  for (int ks = 0; ks < 2; ++ks)
#pragma unroll
    for (int mf = 0; mf < 2; ++mf)
      ap[ks][mf] = wt + ((size_t)(c0 * 4) * K
                  + (size_t)((ks * 2 + lhi) * K + k0 + mf * 32 + l31)) * 8;

  f32x16 acc[2][2] = {};

#define STAGE(BSEL, CI)                                                          \
  {                                                                              \
    _Pragma("unroll")                                                            \
    for (int it = 0; it < 6; ++it) {                                             \
      const unsigned short* g = act + ((size_t)g16[it] + (size_t)(CI) * 4 * HW) * 8; \
      __builtin_amdgcn_global_load_lds(                                          \
          (const __attribute__((address_space(1))) unsigned int*)g,              \
          (__attribute__((address_space(3))) unsigned int*)                      \
              &smem[(BSEL) * 12288 + (it * 256 + wid * 64) * 8],                 \
          16, 0, 0);                                                             \
    }                                                                            \
  }

  STAGE(0, c0)

  for (int i = 0; i < cps; ++i) {
    __syncthreads();
    const int boff = (i & 1) * 12288;
    const unsigned short* aw[2][2];
    short8 acur[2][2], anx[2][2];
#pragma unroll
    for (int ks = 0; ks < 2; ++ks)
#pragma unroll
      for (int mf = 0; mf < 2; ++mf) {
        aw[ks][mf] = ap[ks][mf];
        acur[ks][mf] = *(const short8*)aw[ks][mf];
        aw[ks][mf] += tapStep;
      }
#pragma unroll
    for (int tap = 0; tap < 9; ++tap) {
      if (tap < 8) {
#pragma unroll
        for (int ks = 0; ks < 2; ++ks)
#pragma unroll
          for (int mf = 0; mf < 2; ++mf) {
            anx[ks][mf] = *(const short8*)aw[ks][mf];
            aw[ks][mf] += tapStep;
          }
      }
      if (tap == 7 && i + 1 < cps) STAGE((i & 1) ^ 1, c0 + i + 1)
      const int ty = tap / 3, txx = tap - ty * 3;
      const int toff = (ty * 18 + txx) * 8;
      short8 b[2][2];
#pragma unroll
      for (int ks = 0; ks < 2; ++ks)
#pragma unroll
        for (int nf = 0; nf < 2; ++nf)
          b[nf][ks] = *(const short8*)&smem[boff + bb8[ks][nf] + toff];
#pragma unroll
      for (int ks = 0; ks < 2; ++ks)
#pragma unroll
        for (int mf = 0; mf < 2; ++mf)
#pragma unroll
          for (int nf = 0; nf < 2; ++nf)
            acc[mf][nf] = __builtin_amdgcn_mfma_f32_32x32x16_bf16(
                acur[ks][mf], b[nf][ks], acc[mf][nf], 0, 0, 0);
#pragma unroll
      for (int ks = 0; ks < 2; ++ks)
#pragma unroll
        for (int mf = 0; mf < 2; ++mf)
          acur[ks][mf] = anx[ks][mf];
    }
#pragma unroll
    for (int ks = 0; ks < 2; ++ks)
#pragma unroll
      for (int mf = 0; mf < 2; ++mf)
        ap[ks][mf] += chunkStep;
  }

  if (S > 1) {
    // bf16 partial write, NC8HW8 ordering; pixel is GLOBAL (h0/w0 applied).
    unsigned short* P = partial + (size_t)sp * ((size_t)4 * K * HW);
#pragma unroll
    for (int mf = 0; mf < 2; ++mf)
#pragma unroll
      for (int nf = 0; nf < 2; ++nf) {
        int p = pbase + nf * 32 + l31;
        int gp = (h0 + (p >> 4)) * W + (w0 + (p & 15));
#pragma unroll
        for (int q = 0; q < 4; ++q) {
          size_t ad = ((size_t)(n * K8 + (k0 >> 3) + mf * 4 + q) * HW + gp) * 8 + 4 * lhi;
          short4v v = { (short)f2bf(acc[mf][nf][4 * q]),
                        (short)f2bf(acc[mf][nf][4 * q + 1]),
                        (short)f2bf(acc[mf][nf][4 * q + 2]),
                        (short)f2bf(acc[mf][nf][4 * q + 3]) };
          *(short4v*)(P + ad) = v;
        }
      }
    return;
  }

  // S==1 epilogue: bias + relu + pack bf16 via LDS transpose
  __syncthreads();
#pragma unroll
  for (int mf = 0; mf < 2; ++mf)
#pragma unroll
    for (int nf = 0; nf < 2; ++nf) {
      int pix = pbase + nf * 32 + l31;
#pragma unroll
      for (int rp = 0; rp < 8; ++rp) {
        const int r0 = rp * 2;
        int row0 = (r0 & 3) + 8 * (r0 >> 2) + 4 * lhi;
        int c64 = mf * 32 + row0;
        float v0 = acc[mf][nf][r0]     + sbias[c64];
        float v1 = acc[mf][nf][r0 + 1] + sbias[c64 + 1];
        v0 = v0 > 0.f ? v0 : 0.f;
        v1 = v1 > 0.f ? v1 : 0.f;
        unsigned pk = (unsigned)f2bf(v0) | ((unsigned)f2bf(v1) << 16);
        int chh = mf * 4 + (r0 >> 2);
        int clo = (r0 & 3) + 4 * lhi;
        *(unsigned*)&smem[((chh * 256 + pix) * 8 + clo)] = pk;
      }
    }
  __syncthreads();
#pragma unroll
  for (int i = 0; i < 8; ++i) {
    int slot = i * 256 + tid;
    int ch = slot >> 8;
    int p = slot & 255;
    int py = p >> 4, px = p & 15;
    short8 v = *(const short8*)&smem[slot * 8];
    *(short8*)(out + (((size_t)(n * K8 + (k0 >> 3) + ch) * H + h0 + py) * W + w0 + px) * 8) = v;
  }
#undef STAGE
}

// ---------------------------------------------------------------------------
// combine bf16 split-C partials: sum(fp32) + bias + relu + pack bf16 NC8HW8
// ---------------------------------------------------------------------------
__global__ void combine_bias_relu(const unsigned short* __restrict__ P,
                                  const float* __restrict__ bias,
                                  unsigned short* __restrict__ out, int S, int K8, int HW,
                                  int total8) {
  int idx = blockIdx.x * 256 + threadIdx.x;
  if (idx >= total8) return;
  int k8 = (idx / HW) % K8;
  const unsigned short* p = P + (size_t)idx * 8;
  size_t stride = (size_t)total8 * 8;
  float v[8];
#pragma unroll
  for (int c = 0; c < 8; ++c) v[c] = bf2f(p[c]);
  for (int s = 1; s < S; ++s) {
#pragma unroll
    for (int c = 0; c < 8; ++c) v[c] += bf2f(p[(size_t)s * stride + c]);
  }
  short8 r;
#pragma unroll
  for (int c = 0; c < 8; ++c) {
    float x = v[c] + bias[k8 * 8 + c];
    x = x > 0.f ? x : 0.f;
    r[c] = (short)f2bf(x);
  }
  *(short8*)(out + (size_t)idx * 8) = r;
}

// ---------------------------------------------------------------------------
// FUSED: S-way bf16 partial sum + bias + ReLU (conv output "ll") + wavelet
// unpool + rpad(1)+crop shift. P at conv res Hh x Wh, out NC8HW8 2Hh x 2Wh.
// ---------------------------------------------------------------------------
__global__ void unpool_shift_fused(const unsigned short* __restrict__ P,
                                   const float* __restrict__ bias,
                                   const float* __restrict__ lh, const float* __restrict__ hl,
                                   const float* __restrict__ hh, unsigned short* __restrict__ out,
                                   int C8, int Hh, int Wh, int S, int total) {
  int idx = blockIdx.x * 256 + threadIdx.x;
  if (idx >= total) return;
  const int Ho = 2 * Hh, Wo = 2 * Wh;
  int j = idx % Wo; int t = idx / Wo;
  int i = t % Ho; t /= Ho;
  int ch = t % C8; int n = t / C8;
  int si = (i == 0) ? 1 : i - 1;
  int sj = (j == 0) ? 1 : j - 1;
  float sa = (si & 1) ? 1.f : -1.f;
  float sb = (sj & 1) ? 1.f : -1.f;
  int hy = si >> 1, hx = sj >> 1;
  size_t HWh = (size_t)Hh * Wh;
  const size_t sstr = (size_t)4 * (C8 * 8) * HWh;       // elems per split
  size_t lbase = ((size_t)(n * C8 + ch) * HWh + hy * Wh + hx) * 8;
  float ll[8];
  {
    short8 v0 = *(const short8*)(P + lbase);
#pragma unroll
    for (int cl = 0; cl < 8; ++cl) ll[cl] = bf2f((unsigned short)v0[cl]);
  }
  for (int s = 1; s < S; ++s) {
    short8 vs = *(const short8*)(P + (size_t)s * sstr + lbase);
#pragma unroll
    for (int cl = 0; cl < 8; ++cl) ll[cl] += bf2f((unsigned short)vs[cl]);
  }
#pragma unroll
  for (int cl = 0; cl < 8; ++cl) {
    float x = ll[cl] + bias[ch * 8 + cl];
    ll[cl] = x > 0.f ? x : 0.f;
  }
  size_t bb = ((size_t)(n * C8 + ch) * 8 * Hh + hy) * Wh + hx;
  short8 res;
#pragma unroll
  for (int cl = 0; cl < 8; ++cl) {
    float v = 0.5f * (ll[cl] + sb * lh[bb + cl * HWh] + sa * hl[bb + cl * HWh]
                      + sa * sb * hh[bb + cl * HWh]);
    res[cl] = (short)f2bf(v);
  }
  *(short8*)(out + (size_t)idx * 8) = res;
}

// ---------------------------------------------------------------------------
// Final unpool + rpad, QUAD version: one thread per (img, row-group, col-pair).
// Row groups: g=0 -> row 0 only (== row 2's math, sa=+1, hy=0);
// g in [1,128] -> rows 2g-1 (sa=-1) and 2g (sa=+1), hy=g-1;
// g=129 -> row 257 only (sa=-1, hy=127). Cols as before (sb=+1 even, -1 odd).
// ---------------------------------------------------------------------------
__global__ void unpool_rpad_final_v3(const unsigned short* __restrict__ ll,
                                     const float* __restrict__ lh, const float* __restrict__ hl,
                                     const float* __restrict__ hh, float* __restrict__ out) {
  const int img = blockIdx.y;                 // n*64 + c
  int idx = blockIdx.x * 256 + threadIdx.x;   // over 130 groups * 129 pairs
  if (idx >= 130 * 129) return;
  int g = idx / 129, jm = idx - g * 129;
  const int n = img >> 6, c = img & 63;

  int hy = (g == 0) ? 0 : (g == 129 ? 127 : g - 1);
  int hx0 = (jm == 0) ? 0 : jm - 1;        // col even, sb=+1
  int hx1 = (jm == 128) ? 127 : jm;        // col odd,  sb=-1

  size_t lb = ((size_t)(n * 8 + (c >> 3)) * 16384 + hy * 128) * 8 + (c & 7);
  float ll0 = bf2f(ll[lb + hx0 * 8]);
  float ll1 = bf2f(ll[lb + hx1 * 8]);

  size_t bb = ((size_t)img * 128 + hy) * 128;
  float l0 = lh[bb + hx0], G0 = hl[bb + hx0], h0 = hh[bb + hx0];
  float l1 = lh[bb + hx1], G1 = hl[bb + hx1], h1 = hh[bb + hx1];

  float e0 = ll0 + l0, f0 = G0 + h0;   // col-even combo
  float e1 = ll1 - l1, f1 = G1 - h1;   // col-odd combo
  float2 rm = make_float2(0.5f * (e0 - f0), 0.5f * (e1 - f1));  // sa = -1
  float2 rp = make_float2(0.5f * (e0 + f0), 0.5f * (e1 + f1));  // sa = +1

  float* obase = out + (size_t)img * 258 * 258 + 2 * jm;
  if (g == 0) {
    *(float2*)&obase[0] = rp;                         // row 0
  } else if (g == 129) {
    *(float2*)&obase[(size_t)257 * 258] = rm;         // row 257
  } else {
    *(float2*)&obase[(size_t)(2 * g - 1) * 258] = rm; // odd row, sa=-1
    *(float2*)&obase[(size_t)(2 * g) * 258]     = rp; // even row, sa=+1
  }
}

// ---------------------------------------------------------------------------
// AdaIN support
// ---------------------------------------------------------------------------
__global__ void pack_masks(const float* __restrict__ cmask, const float* __restrict__ smask,
                           unsigned* __restrict__ cbits, unsigned* __restrict__ sbits) {
  int idx = blockIdx.x * 256 + threadIdx.x;
  if (idx >= 16384) return;
  int h = idx >> 7, w = idx & 127;
  unsigned cb = 0, sb = 0;
#pragma unroll
  for (int k = 0; k < 8; ++k) {
    int off = (k * 256 + 2 * h) * 256 + 2 * w;
    if (cmask[off] != 0.f) cb |= (1u << k);
    if (smask[off] != 0.f) sb |= (1u << k);
  }
  cbits[idx] = cb;
  sbits[idx] = sb;
}

__global__ __launch_bounds__(1024) void mask_flags(
    const float* __restrict__ cmask, const float* __restrict__ smask,
    float* __restrict__ flagc, float* __restrict__ sany) {
  int k = blockIdx.x;
  const float* cm = cmask + (size_t)k * 65536;
  const float* sm = smask + (size_t)k * 65536;
  int ca = 0, sa = 0;
  for (int i = threadIdx.x; i < 65536; i += 1024) {
    ca |= (cm[i] != 0.f);
    sa |= (sm[i] != 0.f);
  }
#pragma unroll
  for (int off = 32; off > 0; off >>= 1) {
    ca |= __shfl_xor(ca, off, 64);
    sa |= __shfl_xor(sa, off, 64);
  }
  __shared__ int rc[16], rs[16];
  int wv = threadIdx.x >> 6;
  if ((threadIdx.x & 63) == 0) { rc[wv] = ca; rs[wv] = sa; }
  __syncthreads();
  if (threadIdx.x == 0) {
    int c = 0, s = 0;
#pragma unroll
    for (int i = 0; i < 16; ++i) { c |= rc[i]; s |= rs[i]; }
    flagc[k] = c ? 1.f : 0.f;
    sany[k]  = s ? 1.f : 0.f;
  }
}

__global__ __launch_bounds__(256) void masked_stats_bf16(
    const unsigned short* __restrict__ feat, const unsigned* __restrict__ bits,
    float* __restrict__ outp, int NC) {
  constexpr int NV = 24;
  int b = blockIdx.x; int n = b >> 7, c = b & 127;
  const int sp = blockIdx.y;
  const unsigned short* f = feat + (size_t)(n * 16 + (c >> 3)) * 16384 * 8 + (c & 7);
  float acc[NV];
#pragma unroll
  for (int j = 0; j < NV; ++j) acc[j] = 0.f;
  const int p0 = sp * 4096;
  for (int it = 0; it < 16; ++it) {
    int i = p0 + it * 256 + threadIdx.x;
    float v = bf2f(f[(size_t)i * 8]) + EPSF;
    float nz = (v != 0.f) ? 1.f : 0.f;
    float v2 = v * v;
    unsigned m = bits[i];
#pragma unroll
    for (int k = 0; k < 8; ++k) {
      float mk = (float)((m >> k) & 1u);
      acc[k * 3 + 0] += mk * nz;
      acc[k * 3 + 1] += mk * v;
      acc[k * 3 + 2] += mk * v2;
    }
  }
#pragma unroll
  for (int j = 0; j < NV; ++j) {
    float v = acc[j];
#pragma unroll
    for (int off = 32; off > 0; off >>= 1) v += __shfl_xor(v, off, 64);
    acc[j] = v;
  }
  __shared__ float red[4][NV];
  int lane = threadIdx.x & 63, wv = threadIdx.x >> 6;
  if (lane == 0) {
#pragma unroll
    for (int j = 0; j < NV; ++j) red[wv][j] = acc[j];
  }
  __syncthreads();
  int tid = threadIdx.x;
  if (tid < NV) {
    float s = red[0][tid] + red[1][tid] + red[2][tid] + red[3][tid];
    outp[(sp * NV + tid) * NC + b] = s;
  }
}

__global__ __launch_bounds__(256) void masked_stats_f32g(
    const float* __restrict__ feat, const unsigned* __restrict__ bits,
    float* __restrict__ sstp, float* __restrict__ gstp, int NC) {
  constexpr int NV = 27;
  const int b = blockIdx.x;
  const int sp = blockIdx.y;
  const float* f = feat + (size_t)b * 16384;
  float acc[NV];
#pragma unroll
  for (int j = 0; j < NV; ++j) acc[j] = 0.f;
  const int p0 = sp * 4096;
#pragma unroll 1
  for (int it = 0; it < 4; ++it) {
    int p = p0 + it * 1024 + threadIdx.x * 4;
    float4 v4 = *(const float4*)&f[p];
    uint4 m4 = *(const uint4*)&bits[p];
#pragma unroll
    for (int e = 0; e < 4; ++e) {
      float v = (&v4.x)[e] + EPSF;
      unsigned m = (&m4.x)[e];
      float nz = (v != 0.f) ? 1.f : 0.f;
      float v2 = v * v;
#pragma unroll
      for (int k = 0; k < 8; ++k) {
        float mk = (float)((m >> k) & 1u);
        acc[k * 3 + 0] += mk * nz;
        acc[k * 3 + 1] += mk * v;
        acc[k * 3 + 2] += mk * v2;
      }
      acc[24] += nz; acc[25] += v; acc[26] += v2;
    }
  }
#pragma unroll
  for (int j = 0; j < NV; ++j) {
    float v = acc[j];
#pragma unroll
    for (int off = 32; off > 0; off >>= 1) v += __shfl_xor(v, off, 64);
    acc[j] = v;
  }
  __shared__ float red[4][NV];
  int lane = threadIdx.x & 63, wv = threadIdx.x >> 6;
  if (lane == 0) {
#pragma unroll
    for (int j = 0; j < NV; ++j) red[wv][j] = acc[j];
  }
  __syncthreads();
  int tid = threadIdx.x;
  if (tid < NV) {
    float s = red[0][tid] + red[1][tid] + red[2][tid] + red[3][tid];
    if (tid < 24) sstp[(sp * 24 + tid) * NC + b] = s;
    else gstp[(sp * 3 + (tid - 24)) * NC + b] = s;
  }
}

__global__ void finalize_ss(const float* __restrict__ cstp, const float* __restrict__ sstp,
                            const float* __restrict__ gstp, const float* __restrict__ flagc,
                            const float* __restrict__ sany,
                            float* __restrict__ scal, float* __restrict__ shft, int NC) {
  int idx = blockIdx.x * blockDim.x + threadIdx.x;
  if (idx >= 8 * NC) return;
  int k = idx / NC, b = idx - k * NC;
  bool useg = (sany[k] == 0.f);
  float ccnt = 0.f, cs1 = 0.f, cs2 = 0.f, scnt = 0.f, ss1 = 0.f, ss2 = 0.f;
#pragma unroll
  for (int s = 0; s < 4; ++s) {
    const float* cp = cstp + s * 24 * NC;
    ccnt += cp[(k * 3 + 0) * NC + b];
    cs1  += cp[(k * 3 + 1) * NC + b];
    cs2  += cp[(k * 3 + 2) * NC + b];
    if (useg) {
      const float* gp = gstp + s * 3 * NC;
      scnt += gp[0 * NC + b]; ss1 += gp[1 * NC + b]; ss2 += gp[2 * NC + b];
    } else {
      const float* spp = sstp + s * 24 * NC;
      scnt += spp[(k * 3 + 0) * NC + b];
      ss1  += spp[(k * 3 + 1) * NC + b];
      ss2  += spp[(k * 3 + 2) * NC + b];
    }
  }
  float cmn  = cs1 / fmaxf(ccnt, 1.f);
  float cvv  = (cs2 - ccnt * cmn * cmn) / fmaxf(ccnt - 1.f, 1.f) + EPSF;
  float cstd = sqrtf(cvv);
  float smn  = ss1 / fmaxf(scnt, 1.f);
  float svv  = (ss2 - scnt * smn * smn) / fmaxf(scnt - 1.f, 1.f) + EPSF;
  float sstd = sqrtf(svv);
  float fl = flagc[k];
  float r  = sstd / cstd;
  scal[idx] = fl * r;
  shft[idx] = fl * (smn - cmn * r);
}

__global__ void adain_apply_nc8(const unsigned short* __restrict__ content,
                                const unsigned* __restrict__ bits,
                                const float* __restrict__ scal, const float* __restrict__ shft,
                                unsigned short* __restrict__ out) {
  int ch = blockIdx.x & 15, n = blockIdx.x >> 4;
  __shared__ float ssc[8][8], ssh[8][8];
  if (threadIdx.x < 64) {
    int k = threadIdx.x >> 3, cl = threadIdx.x & 7;
    int c = ch * 8 + cl;
    ssc[k][cl] = scal[k * 512 + n * 128 + c];
    ssh[k][cl] = shft[k * 512 + n * 128 + c];
  }
  __syncthreads();
  const unsigned short* src = content + (size_t)blockIdx.x * 16384 * 8;
  unsigned short* dst = out + (size_t)blockIdx.x * 16384 * 8;
  const int p0 = blockIdx.y * 1024;
  for (int p = p0 + threadIdx.x; p < p0 + 1024; p += 256) {
    unsigned m = bits[p];
    float sc[8], sh[8];
#pragma unroll
    for (int cl = 0; cl < 8; ++cl) { sc[cl] = 0.f; sh[cl] = 0.f; }
    for (int k = 0; k < 8; ++k) {
      if ((m >> k) & 1u) {
#pragma unroll
        for (int cl = 0; cl < 8; ++cl) { sc[cl] += ssc[k][cl]; sh[cl] += ssh[k][cl]; }
      }
    }
    short8 v = *(const short8*)(src + (size_t)p * 8);
    short8 r;
#pragma unroll
    for (int cl = 0; cl < 8; ++cl) {
      float f = bf2f((unsigned short)v[cl]) + EPSF;
      r[cl] = (short)f2bf(f * sc[cl] + sh[cl]);
    }
    *(short8*)(dst + (size_t)p * 8) = r;
  }
}

// ---------------------------------------------------------------------------
static void launch_conv(const unsigned short* act, const unsigned short* wt,
                        const float* bias, unsigned short* out, unsigned short* partial,
                        int C, int K, int H, int W, int S, bool combine, hipStream_t st) {
  dim3 g(W / 16, H / 16, 4 * (K / 64) * S);
  conv3x3_mfma<<<g, 256, 0, st>>>(act, wt, bias, out, partial, C, K, H, W, S);
  if (S > 1 && combine) {
    int total8 = 4 * (K >> 3) * H * W;
    combine_bias_relu<<<(total8 + 255) / 256, 256, 0, st>>>(
        partial, bias, out, S, K >> 3, H * W, total8);
  }
}

extern "C" void kernel_launch(void* const* d_in, const int* in_sizes, int n_in,
                              void* d_out, int out_size, void* d_ws, size_t ws_size,
                              hipStream_t stream) {
  const float* f1   = (const float*)d_in[0];
  const float* f2   = (const float*)d_in[1];
  const float* s2lh = (const float*)d_in[2];
  const float* s2hl = (const float*)d_in[3];
  const float* s2hh = (const float*)d_in[4];
  const float* s1lh = (const float*)d_in[5];
  const float* s1hl = (const float*)d_in[6];
  const float* s1hh = (const float*)d_in[7];
  const float* s0lh = (const float*)d_in[8];
  const float* s0hl = (const float*)d_in[9];
  const float* s0hh = (const float*)d_in[10];
  const float* cmask = (const float*)d_in[11];
  const float* smask = (const float*)d_in[12];
  const float* w11 = (const float*)d_in[13]; const float* b11 = (const float*)d_in[14];
  const float* w12 = (const float*)d_in[15]; const float* b12 = (const float*)d_in[16];
  const float* w21 = (const float*)d_in[17]; const float* b21 = (const float*)d_in[18];
  const float* w22 = (const float*)d_in[19]; const float* b22 = (const float*)d_in[20];
  const float* w23 = (const float*)d_in[21]; const float* b23 = (const float*)d_in[22];
  const float* w24 = (const float*)d_in[23]; const float* b24 = (const float*)d_in[24];
  const float* w31 = (const float*)d_in[25]; const float* b31 = (const float*)d_in[26];
  const float* w32 = (const float*)d_in[27]; const float* b32 = (const float*)d_in[28];
  const float* w33 = (const float*)d_in[29]; const float* b33 = (const float*)d_in[30];

  // d_out layout: A bf16 [0,16.78MB) B bf16 [16.78,33.55MB)
  //   P bf16 partials [33,554,432, 67,108,864)
  // FINAL kernel writes all of d_out -> its input t12 lives in d_ws.
  unsigned short* A = (unsigned short*)d_out;
  unsigned short* B = A + 8388608;
  unsigned short* P = (unsigned short*)((char*)d_out + 33554432);

  // workspace layout (bytes)
  char* wsb = (char*)d_ws;
  unsigned short* wtb = (unsigned short*)wsb;          // 5,971,968 elems bf16
  const size_t o11 = 0,        o12 = 2359296, o21 = 3538944, o22 = 4128768,
               o23 = 4718592,  o24 = 5308416, o31 = 5603328, o32 = 5750784,
               o33 = 5898240;
  unsigned short* f2c = (unsigned short*)(wsb + 11943936);   // 2,097,152 elems
  unsigned* cbits = (unsigned*)(wsb + 16138240);
  unsigned* sbits = (unsigned*)(wsb + 16203776);
  float* cstp = (float*)(wsb + 16269312);                    // 4*24*512
  float* sstp = (float*)(wsb + 16465920);                    // 4*24*512
  float* gstp = (float*)(wsb + 16662528);                    // 4*3*512
  float* scal = (float*)(wsb + 16687104);
  float* shft = (float*)(wsb + 16703488);
  float* flagc = (float*)(wsb + 16719872);
  float* sany  = (float*)(wsb + 16719904);
  unsigned short* t12 = (unsigned short*)wsb;  // overlaps consumed Wt buffers

  const int NC = 512;

  wt_prep<<<dim3((512 * 64 + 255) / 256, 9), 256, 0, stream>>>(w11, wtb + o11, 512, 512);
  wt_prep<<<dim3((256 * 64 + 255) / 256, 9), 256, 0, stream>>>(w12, wtb + o12, 512, 256);
  wt_prep<<<dim3((256 * 32 + 255) / 256, 9), 256, 0, stream>>>(w21, wtb + o21, 256, 256);
  wt_prep<<<dim3((256 * 32 + 255) / 256, 9), 256, 0, stream>>>(w22, wtb + o22, 256, 256);
  wt_prep<<<dim3((256 * 32 + 255) / 256, 9), 256, 0, stream>>>(w23, wtb + o23, 256, 256);
  wt_prep<<<dim3((128 * 32 + 255) / 256, 9), 256, 0, stream>>>(w24, wtb + o24, 256, 128);
  wt_prep<<<dim3((128 * 16 + 255) / 256, 9), 256, 0, stream>>>(w31, wtb + o31, 128, 128);
  wt_prep<<<dim3((128 * 16 + 255) / 256, 9), 256, 0, stream>>>(w32, wtb + o32, 128, 128);
  wt_prep<<<dim3(( 64 * 16 + 255) / 256, 9), 256, 0, stream>>>(w33, wtb + o33, 128,  64);

  nchw_to_nc8<<<(262144 + 255) / 256, 256, 0, stream>>>(f2, f2c, 64, 1024, 262144);

  pack_masks<<<64, 256, 0, stream>>>(cmask, smask, cbits, sbits);
  mask_flags<<<8, 1024, 0, stream>>>(cmask, smask, flagc, sany);

  // conv chain, MINIMAL splits (r13 showed conv time S-invariant; smaller S
  // halves combine / fused-unpool partial reads):
  // L1 S=4, L2 S=8 (fused), L3-5 S=2, L6 S=4 (fused), L7/8 S=1, L9 S=2
  launch_conv(f2c, wtb + o11, b11, A, P, 512, 512, 32, 32, 4, true, stream);
  launch_conv(A,   wtb + o12, b12, B, P, 512, 256, 32, 32, 8, false, stream);
  unpool_shift_fused<<<(524288 + 255) / 256, 256, 0, stream>>>(
      P, b12, s2lh, s2hl, s2hh, A, 32, 32, 32, 8, 524288);
  launch_conv(A,   wtb + o21, b21, B, P, 256, 256, 64, 64, 2, true, stream);
  launch_conv(B,   wtb + o22, b22, A, P, 256, 256, 64, 64, 2, true, stream);
  launch_conv(A,   wtb + o23, b23, B, P, 256, 256, 64, 64, 2, true, stream);
  launch_conv(B,   wtb + o24, b24, A, P, 256, 128, 64, 64, 4, false, stream);
  unpool_shift_fused<<<(1048576 + 255) / 256, 256, 0, stream>>>(
      P, b24, s1lh, s1hl, s1hh, B, 16, 64, 64, 4, 1048576);

  // AdaIN: content=B (bf16), style=f1 (fp32) -> A
  masked_stats_bf16<<<dim3(512, 4), 256, 0, stream>>>(B, cbits, cstp, NC);
  masked_stats_f32g<<<dim3(512, 4), 256, 0, stream>>>(f1, sbits, sstp, gstp, NC);
  finalize_ss<<<16, 256, 0, stream>>>(cstp, sstp, gstp, flagc, sany, scal, shft, NC);
  adain_apply_nc8<<<dim3(64, 16), 256, 0, stream>>>(B, cbits, scal, shft, A);

  launch_conv(A, wtb + o31, b31, B, P, 128, 128, 128, 128, 1, true, stream);
  launch_conv(B, wtb + o32, b32, A, P, 128, 128, 128, 128, 1, true, stream);
  launch_conv(A, wtb + o33, b33, t12, P, 128, 64, 128, 128, 2, true, stream);

  // final: QUAD unpool + rpad, reads t12 (d_ws) -> all of d_out
  unpool_rpad_final_v3<<<dim3(66, 256), 256, 0, stream>>>(
      t12, s0lh, s0hl, s0hh, (float*)d_out);
}